// Round 16
// baseline (645.492 us; speedup 1.0000x reference)
//
#include <hip/hip_runtime.h>

// ---------------- types & helpers ----------------
typedef __attribute__((ext_vector_type(8))) short short8;   // 8 bf16 (4 VGPR)
typedef __attribute__((ext_vector_type(4))) float f32x4;
typedef _Float16 f16;
typedef __attribute__((ext_vector_type(2))) _Float16 f16x2;
typedef __attribute__((ext_vector_type(8))) _Float16 f16x8;

__device__ inline float bf2f(unsigned short u){
  union{float f; unsigned u32;} x; x.u32 = ((unsigned)u) << 16; return x.f;
}
__device__ inline unsigned short f2bf(float f){
  union{float f; unsigned u;} x; x.f = f;
  unsigned r = (x.u + 0x7FFFu + ((x.u >> 16) & 1u)) >> 16;
  return (unsigned short)r;
}

#if defined(__has_builtin)
#  if __has_builtin(__builtin_amdgcn_fdot2)
#    define HAS_FDOT2 1
#  endif
#endif
__device__ inline float dot2f(f16x2 a, f16x2 b, float c){
#ifdef HAS_FDOT2
  return __builtin_amdgcn_fdot2(a, b, c, false);
#else
  return c + (float)a.x * (float)b.x + (float)a.y * (float)b.y;
#endif
}
__device__ inline f16x2 asf16x2(int v){ return __builtin_bit_cast(f16x2, v); }
__device__ inline int pack2(float lo, float hi){
  f16x2 p = f16x2{(f16)lo, (f16)hi};
  return __builtin_bit_cast(int, p);
}

__device__ inline float sigmoidf_(float x){ return 1.f / (1.f + __expf(-x)); }
__device__ inline float tanh_fast(float x){ float e = __expf(2.f * x); return 1.f - 2.f / (e + 1.f); }

// DPP quad-permute butterfly adds (VALU pipe)
__device__ inline float dpp_xor1(float x){
  return __int_as_float(__builtin_amdgcn_update_dpp(0, __float_as_int(x), 0xB1, 0xF, 0xF, true));
}
__device__ inline float dpp_xor2(float x){
  return __int_as_float(__builtin_amdgcn_update_dpp(0, __float_as_int(x), 0x4E, 0xF, 0xF, true));
}
// lane^4 exchange via ds_swizzle BitMode: offset = (4<<10)|0x1F
__device__ inline float swz_xor4(float x){
  return __int_as_float(__builtin_amdgcn_ds_swizzle(__float_as_int(x), 0x101F));
}

__device__ inline void load8bf(const unsigned short* p, float* o){
  uint4 q = *(const uint4*)p;
  o[0]=bf2f((unsigned short)(q.x & 0xffffu)); o[1]=bf2f((unsigned short)(q.x >> 16));
  o[2]=bf2f((unsigned short)(q.y & 0xffffu)); o[3]=bf2f((unsigned short)(q.y >> 16));
  o[4]=bf2f((unsigned short)(q.z & 0xffffu)); o[5]=bf2f((unsigned short)(q.z >> 16));
  o[6]=bf2f((unsigned short)(q.w & 0xffffu)); o[7]=bf2f((unsigned short)(q.w >> 16));
}

// async global->LDS, 16 bytes per lane (lds dest = wave-uniform base + lane*16)
#define GLL16(g, l) __builtin_amdgcn_global_load_lds(                      \
    (const __attribute__((address_space(1))) void*)(g),                    \
    (__attribute__((address_space(3))) void*)(l), 16, 0, 0)

// ---------------- fused weight conversion (8 segments, one launch) ----------------
__global__ __launch_bounds__(256) void conv_all_k(
    const float* __restrict__ s0, const float* __restrict__ s1,
    const float* __restrict__ s2, const float* __restrict__ s3,
    const float* __restrict__ s4, const float* __restrict__ s5,
    const float* __restrict__ s6, const float* __restrict__ s7,
    unsigned short* __restrict__ d0, unsigned short* __restrict__ d1,
    unsigned short* __restrict__ d2, f16* __restrict__ d3,
    unsigned short* __restrict__ d4, unsigned short* __restrict__ d5,
    unsigned short* __restrict__ d6, unsigned short* __restrict__ d7)
{
  int i = blockIdx.x * 256 + threadIdx.x;
  if (i >= 516096) return;
  const float* src; int local; int mode = 0; unsigned short* dst = nullptr; f16* dstf = nullptr;
  if (i < 196608)      { src = s0; local = i;           dst = d0; }
  else if (i < 204800) { src = s1; local = i - 196608;  dst = d1; }
  else if (i < 253952) { src = s2; local = i - 204800;  dst = d2; }
  else if (i < 303104) { src = s3; local = i - 253952;  dstf = d3; mode = 1; }
  else if (i < 319488) { src = s4; local = i - 303104;  dst = d4; }
  else if (i < 368640) { src = s5; local = i - 319488;  dst = d5; }
  else if (i < 385024) { src = s6; local = i - 368640;  dst = d6; }
  else                 { src = s7; local = i - 385024;  dst = d7; }
  float4 v = ((const float4*)src)[local];
  if (mode == 0) {
    union { unsigned short s[4]; uint2 q; } u;
    u.s[0]=f2bf(v.x); u.s[1]=f2bf(v.y); u.s[2]=f2bf(v.z); u.s[3]=f2bf(v.w);
    ((uint2*)dst)[local] = u.q;
  } else {
    union { f16 s[4]; uint2 q; } u;
    u.s[0]=(f16)v.x; u.s[1]=(f16)v.y; u.s[2]=(f16)v.z; u.s[3]=(f16)v.w;
    ((uint2*)dstf)[local] = u.q;
  }
}

// pred_W [190][256] -> [192][256] zero-padded bf16; pred_b -> [192] zero-padded f32
__global__ __launch_bounds__(256) void pred_pad_k(const float* __restrict__ W,
                                                  const float* __restrict__ b,
                                                  unsigned short* __restrict__ Wd,
                                                  float* __restrict__ bd){
  int i = blockIdx.x * 256 + threadIdx.x;   // 192*256 threads
  int j = i >> 8;
  Wd[i] = (j < 190) ? f2bf(W[i]) : (unsigned short)0;
  if (i < 192) bd[i] = (i < 190) ? b[i] : 0.f;
}

// ---------------- 128x128-tile MFMA GEMM (m97 structure) ----------------
// A_MODE: 0 = bf16 via global_load_lds; 1 = f32 reg-convert; 2 = bf16 minus mean.
template<int OUT_T, bool BN, int A_MODE>
__global__ __launch_bounds__(256) void gemm128_k(
    const void* __restrict__ Ap, const unsigned short* __restrict__ Bw,
    const float* __restrict__ bias,
    const float* __restrict__ gam, const float* __restrict__ bet,
    const float* __restrict__ mu,  const float* __restrict__ var,
    void* __restrict__ Cp, int M, int N, int K)
{
  __shared__ __align__(16) unsigned short As[4096];   // [128][32]
  __shared__ __align__(16) unsigned short Bs[4096];
  const int tid  = threadIdx.x;
  const int lane = tid & 63, wid = tid >> 6;
  const int wm = wid & 1, wn = wid >> 1;
  const int bm = blockIdx.y << 7, bn = blockIdx.x << 7;
  const int rA = tid >> 2, seg = tid & 3;

  f32x4 acc[4][4];
  #pragma unroll
  for (int i = 0; i < 4; i++)
    #pragma unroll
    for (int j = 0; j < 4; j++)
      acc[i][j] = f32x4{0.f, 0.f, 0.f, 0.f};

  const unsigned short* Abf = (const unsigned short*)Ap;
  const float* Af = (const float*)Ap;
  char* asb = (char*)As;
  char* bsb = (char*)Bs;
  char* asw = asb + wid * 1024;
  char* bsw = bsb + wid * 1024;

  for (int k0 = 0; k0 < K; k0 += 32) {
    if (A_MODE == 1) {
      #pragma unroll
      for (int beta = 0; beta < 2; beta++) {
        const float* src = Af + (size_t)(bm + rA + beta * 64) * K + k0 + seg * 8;
        float4 v0 = *(const float4*)src;
        float4 v1 = *(const float4*)(src + 4);
        union { unsigned short s[8]; uint4 q; } u;
        u.s[0]=f2bf(v0.x); u.s[1]=f2bf(v0.y); u.s[2]=f2bf(v0.z); u.s[3]=f2bf(v0.w);
        u.s[4]=f2bf(v1.x); u.s[5]=f2bf(v1.y); u.s[6]=f2bf(v1.z); u.s[7]=f2bf(v1.w);
        *(uint4*)(asb + beta * 4096 + tid * 16) = u.q;
      }
    } else if (A_MODE == 2) {
      const float* mrow = mu + (size_t)(bm >> 7) * 256 + k0 + seg * 8;
      float4 m0 = *(const float4*)mrow;
      float4 m1 = *(const float4*)(mrow + 4);
      #pragma unroll
      for (int beta = 0; beta < 2; beta++) {
        const unsigned short* src = Abf + (size_t)(bm + rA + beta * 64) * K + k0 + seg * 8;
        float av[8];
        load8bf(src, av);
        union { unsigned short s[8]; uint4 q; } u;
        u.s[0]=f2bf(av[0]-m0.x); u.s[1]=f2bf(av[1]-m0.y); u.s[2]=f2bf(av[2]-m0.z); u.s[3]=f2bf(av[3]-m0.w);
        u.s[4]=f2bf(av[4]-m1.x); u.s[5]=f2bf(av[5]-m1.y); u.s[6]=f2bf(av[6]-m1.z); u.s[7]=f2bf(av[7]-m1.w);
        *(uint4*)(asb + beta * 4096 + tid * 16) = u.q;
      }
    } else {
      GLL16(Abf + (size_t)(bm + rA)      * K + k0 + seg * 8, asw);
      GLL16(Abf + (size_t)(bm + rA + 64) * K + k0 + seg * 8, asw + 4096);
    }
    GLL16(Bw + (size_t)(bn + rA)      * K + k0 + seg * 8, bsw);
    GLL16(Bw + (size_t)(bn + rA + 64) * K + k0 + seg * 8, bsw + 4096);
    __syncthreads();

    short8 a[4], b[4];
    #pragma unroll
    for (int f = 0; f < 4; f++) {
      int ra = wm * 64 + f * 16 + (lane & 15);
      a[f] = *(const short8*)(asb + ra * 64 + (lane >> 4) * 16);
      int rb = wn * 64 + f * 16 + (lane & 15);
      b[f] = *(const short8*)(bsb + rb * 64 + (lane >> 4) * 16);
    }
    #pragma unroll
    for (int fm = 0; fm < 4; fm++)
      #pragma unroll
      for (int fn = 0; fn < 4; fn++)
        acc[fm][fn] = __builtin_amdgcn_mfma_f32_16x16x32_bf16(a[fm], b[fn], acc[fm][fn], 0, 0, 0);
    __syncthreads();
  }

  #pragma unroll
  for (int fn = 0; fn < 4; fn++) {
    int col = bn + wn * 64 + fn * 16 + (lane & 15);
    float bs = bias[col];
    float sc = 1.f, sh = 0.f;
    if (BN) { float s = gam[col] * rsqrtf(var[col] + 1e-5f); sc = s; sh = bet[col] - mu[col] * s; }
    #pragma unroll
    for (int fm = 0; fm < 4; fm++) {
      int row = bm + wm * 64 + fm * 16 + ((lane >> 4) << 2);
      #pragma unroll
      for (int j = 0; j < 4; j++) {
        float v = acc[fm][fn][j] + bs;
        if (BN) { v = v * sc + sh; v = fmaxf(v, 0.f); }
        size_t idx = (size_t)(row + j) * N + col;
        if (OUT_T == 1) ((f16*)Cp)[idx] = (f16)v;
        else            ((unsigned short*)Cp)[idx] = f2bf(v);
      }
    }
  }
}

// ---------------- 64-tile MFMA GEMM (kept for logits, N=192) ----------------
template<int OUT_T, bool BN, bool AF32>
__global__ __launch_bounds__(256) void gemm_k(
    const void* __restrict__ Ap, const unsigned short* __restrict__ Bw,
    const float* __restrict__ bias,
    const float* __restrict__ gam, const float* __restrict__ bet,
    const float* __restrict__ mu,  const float* __restrict__ var,
    void* __restrict__ Cp, int M, int N, int K)
{
  __shared__ unsigned short As[64][40];
  __shared__ unsigned short Bs[64][40];
  const int tid  = threadIdx.x;
  const int lane = tid & 63, wid = tid >> 6;
  const int wm = wid & 1, wn = wid >> 1;
  const int bm = blockIdx.y << 6, bn = blockIdx.x << 6;
  const int srow = tid >> 2, sseg = tid & 3;

  f32x4 acc[2][2];
  #pragma unroll
  for (int i = 0; i < 2; i++)
    #pragma unroll
    for (int j = 0; j < 2; j++)
      acc[i][j] = f32x4{0.f, 0.f, 0.f, 0.f};

  const unsigned short* Abf = (const unsigned short*)Ap;
  const float* Af = (const float*)Ap;

  for (int k0 = 0; k0 < K; k0 += 32) {
    if (AF32) {
      const float* src = Af + (size_t)(bm + srow) * K + k0 + sseg * 8;
      float4 v0 = *(const float4*)(src);
      float4 v1 = *(const float4*)(src + 4);
      union { unsigned short s[8]; uint4 q; } u;
      u.s[0]=f2bf(v0.x); u.s[1]=f2bf(v0.y); u.s[2]=f2bf(v0.z); u.s[3]=f2bf(v0.w);
      u.s[4]=f2bf(v1.x); u.s[5]=f2bf(v1.y); u.s[6]=f2bf(v1.z); u.s[7]=f2bf(v1.w);
      *(uint4*)&As[srow][sseg * 8] = u.q;
    } else {
      *(uint4*)&As[srow][sseg * 8] =
          *(const uint4*)(Abf + (size_t)(bm + srow) * K + k0 + sseg * 8);
    }
    *(uint4*)&Bs[srow][sseg * 8] =
        *(const uint4*)(Bw + (size_t)(bn + srow) * K + k0 + sseg * 8);
    __syncthreads();

    short8 a0 = *(const short8*)&As[wm * 32 +      (lane & 15)][(lane >> 4) * 8];
    short8 a1 = *(const short8*)&As[wm * 32 + 16 + (lane & 15)][(lane >> 4) * 8];
    short8 b0 = *(const short8*)&Bs[wn * 32 +      (lane & 15)][(lane >> 4) * 8];
    short8 b1 = *(const short8*)&Bs[wn * 32 + 16 + (lane & 15)][(lane >> 4) * 8];
    acc[0][0] = __builtin_amdgcn_mfma_f32_16x16x32_bf16(a0, b0, acc[0][0], 0, 0, 0);
    acc[0][1] = __builtin_amdgcn_mfma_f32_16x16x32_bf16(a0, b1, acc[0][1], 0, 0, 0);
    acc[1][0] = __builtin_amdgcn_mfma_f32_16x16x32_bf16(a1, b0, acc[1][0], 0, 0, 0);
    acc[1][1] = __builtin_amdgcn_mfma_f32_16x16x32_bf16(a1, b1, acc[1][1], 0, 0, 0);
    __syncthreads();
  }

  #pragma unroll
  for (int fn = 0; fn < 2; fn++) {
    int col = bn + wn * 32 + fn * 16 + (lane & 15);
    float bs = bias[col];
    float sc = 1.f, sh = 0.f;
    if (BN) { float s = gam[col] * rsqrtf(var[col] + 1e-5f); sc = s; sh = bet[col] - mu[col] * s; }
    #pragma unroll
    for (int fm = 0; fm < 2; fm++) {
      int row = bm + wm * 32 + fm * 16 + ((lane >> 4) << 2);
      #pragma unroll
      for (int j = 0; j < 4; j++) {
        float v = acc[fm][fn][j] + bs;
        if (BN) { v = v * sc + sh; v = fmaxf(v, 0.f); }
        size_t idx = (size_t)(row + j) * N + col;
        if (OUT_T == 0)      ((float*)Cp)[idx] = v;
        else if (OUT_T == 1) ((f16*)Cp)[idx]   = (f16)v;
        else                 ((unsigned short*)Cp)[idx] = f2bf(v);
      }
    }
  }
}

// ---------------- GRU scans ----------------
// GRU2 (LDS-minimal): 512 threads, jj = tid>>1, kh = tid&1.
// Gate r: 64 opaque VGPRs. Gates z,n: STREAMED FROM L2 every step (384 KB,
// L2-resident) via 4-deep rolling uint4 buffers (compile-time indices).
// LDS = 16 broadcast h reads + 1 h write per thread/step (was 33 -> issue-bound fix).
__global__ __launch_bounds__(512, 2) void gru2_scan_k(
    const f16* __restrict__ Wf,              // [768][256] f16
    const float* __restrict__ bhh,
    const f16* __restrict__ xp, unsigned short* __restrict__ hs_relu)
{
  const int b = blockIdx.x;
  const int tid = threadIdx.x;
  const int jj = tid >> 1, kh = tid & 1;
  __shared__ __align__(16) f16 hbuf[2][256];

  // gate-r weights in registers (opaque -> non-rematerializable)
  int wri[64];
  #pragma unroll
  for (int i = 0; i < 16; i++) {
    uint4 q = *(const uint4*)&Wf[(size_t)jj * 256 + kh * 128 + i * 8];
    wri[4*i+0] = (int)q.x; wri[4*i+1] = (int)q.y; wri[4*i+2] = (int)q.z; wri[4*i+3] = (int)q.w;
  }
  #pragma unroll
  for (int i = 0; i < 64; i++)
    asm volatile("" : "+v"(wri[i]));

  const f16* zsrc = Wf + (size_t)(256 + jj) * 256 + kh * 128;
  const f16* nsrc = Wf + (size_t)(512 + jj) * 256 + kh * 128;

  const float br = bhh[jj], bz = bhh[jj + 256], bn2 = bhh[jj + 512];
  if (tid < 256) hbuf[0][tid] = (f16)0.f;
  float hprev = 0.f;
  f16 pxr = (f16)0.f, pxz = (f16)0.f, pxn = (f16)0.f;
  if (kh == 0) {
    const f16* x0 = xp + (size_t)(b * 128) * 768;
    pxr = x0[jj]; pxz = x0[256 + jj]; pxn = x0[512 + jj];
  }
  __syncthreads();
  int cur = 0;
  for (int t = 0; t < 128; t++) {
    float xr = (float)pxr, xz = (float)pxz, xn = (float)pxn;
    if (kh == 0) {
      const int tn = (t < 127) ? (t + 1) : 127;
      const f16* xnr = xp + (size_t)(b * 128 + tn) * 768;
      pxr = xnr[jj]; pxz = xnr[256 + jj]; pxn = xnr[512 + jj];
    }
    // prime 4-deep z/n buffers
    uint4 zb[4], nb[4];
    #pragma unroll
    for (int c = 0; c < 4; c++) {
      zb[c] = *(const uint4*)(zsrc + c * 8);
      nb[c] = *(const uint4*)(nsrc + c * 8);
    }
    const char* hb = (const char*)hbuf[cur] + kh * 256;
    float ar = 0.f, az = 0.f, an = 0.f;
    #pragma unroll
    for (int i = 0; i < 16; i++) {
      f16x8 hv = *(const f16x8*)(hb + i * 16);
      f16x8 zv = __builtin_bit_cast(f16x8, zb[i & 3]);
      f16x8 nv = __builtin_bit_cast(f16x8, nb[i & 3]);
      if (i < 12) {
        zb[i & 3] = *(const uint4*)(zsrc + (i + 4) * 8);
        nb[i & 3] = *(const uint4*)(nsrc + (i + 4) * 8);
      }
      #pragma unroll
      for (int u = 0; u < 4; u++) {
        f16x2 hp = f16x2{hv[2*u], hv[2*u+1]};
        ar = dot2f(asf16x2(wri[4*i+u]), hp, ar);
        az = dot2f(f16x2{zv[2*u], zv[2*u+1]}, hp, az);
        an = dot2f(f16x2{nv[2*u], nv[2*u+1]}, hp, an);
      }
    }
    ar += dpp_xor1(ar);
    az += dpp_xor1(az);
    an += dpp_xor1(an);
    if (kh == 0) {
      float r = sigmoidf_(xr + ar + br);
      float z = sigmoidf_(xz + az + bz);
      float n = tanh_fast(xn + r * (an + bn2));
      float hnew = (1.f - z) * n + z * hprev;
      hprev = hnew;
      hbuf[cur ^ 1][jj] = (f16)hnew;
      hs_relu[(size_t)(b * 128 + t) * 256 + jj] = f2bf(fmaxf(hnew, 0.f));
    }
    __syncthreads();
    cur ^= 1;
  }
}

// GRU1: H=128, gates 384. 1024 threads (16 waves/CU -> 4 waves/SIMD):
// jj = tid>>3 (0..127), kh = tid&7 (16-f16 k-slice). Weights: 3 x 8 opaque ints.
// Reduce: quad DPP xor1+xor2 + ds_swizzle xor4.
__global__ __launch_bounds__(1024) void gru1_scan_k(
    const float* __restrict__ Whh, const float* __restrict__ bhh,
    const f16* __restrict__ xp, unsigned short* __restrict__ hs_relu)
{
  const int b = blockIdx.x;
  const int tid = threadIdx.x;
  const int jj = tid >> 3, kh = tid & 7;
  __shared__ __align__(16) f16 hbuf[2][128];

  int wri[8], wzi[8], wni[8];
  #pragma unroll
  for (int i = 0; i < 2; i++) {
    const int kb = kh * 16 + i * 8;
    float4 f0, f1;
    f0 = *(const float4*)&Whh[(size_t)(jj      ) * 128 + kb];
    f1 = *(const float4*)&Whh[(size_t)(jj      ) * 128 + kb + 4];
    wri[4*i+0] = pack2(f0.x, f0.y); wri[4*i+1] = pack2(f0.z, f0.w);
    wri[4*i+2] = pack2(f1.x, f1.y); wri[4*i+3] = pack2(f1.z, f1.w);
    f0 = *(const float4*)&Whh[(size_t)(jj + 128) * 128 + kb];
    f1 = *(const float4*)&Whh[(size_t)(jj + 128) * 128 + kb + 4];
    wzi[4*i+0] = pack2(f0.x, f0.y); wzi[4*i+1] = pack2(f0.z, f0.w);
    wzi[4*i+2] = pack2(f1.x, f1.y); wzi[4*i+3] = pack2(f1.z, f1.w);
    f0 = *(const float4*)&Whh[(size_t)(jj + 256) * 128 + kb];
    f1 = *(const float4*)&Whh[(size_t)(jj + 256) * 128 + kb + 4];
    wni[4*i+0] = pack2(f0.x, f0.y); wni[4*i+1] = pack2(f0.z, f0.w);
    wni[4*i+2] = pack2(f1.x, f1.y); wni[4*i+3] = pack2(f1.z, f1.w);
  }
  #pragma unroll
  for (int i = 0; i < 8; i++)
    asm volatile("" : "+v"(wri[i]), "+v"(wzi[i]), "+v"(wni[i]));

  const float br = bhh[jj], bz = bhh[jj + 128], bn2 = bhh[jj + 256];
  if (tid < 128) hbuf[0][tid] = (f16)0.f;
  float hprev = 0.f;
  f16 pxr = (f16)0.f, pxz = (f16)0.f, pxn = (f16)0.f;
  if (kh == 0) {
    const f16* x0 = xp + (size_t)(b * 128) * 384;
    pxr = x0[jj]; pxz = x0[128 + jj]; pxn = x0[256 + jj];
  }
  __syncthreads();
  int cur = 0;
  for (int t = 0; t < 128; t++) {
    float xr = (float)pxr, xz = (float)pxz, xn = (float)pxn;
    if (kh == 0) {
      const int tn = (t < 127) ? (t + 1) : 127;
      const f16* xnr = xp + (size_t)(b * 128 + tn) * 384;
      pxr = xnr[jj]; pxz = xnr[128 + jj]; pxn = xnr[256 + jj];
    }
    const char* hb = (const char*)hbuf[cur] + kh * 32;
    float ar = 0.f, az = 0.f, an = 0.f;
    #pragma unroll
    for (int c = 0; c < 2; c++) {
      f16x8 hv = *(const f16x8*)(hb + c * 16);
      #pragma unroll
      for (int u = 0; u < 4; u++) {
        f16x2 hp = f16x2{hv[2*u], hv[2*u+1]};
        ar = dot2f(asf16x2(wri[4*c+u]), hp, ar);
        az = dot2f(asf16x2(wzi[4*c+u]), hp, az);
        an = dot2f(asf16x2(wni[4*c+u]), hp, an);
      }
    }
    ar += dpp_xor1(ar); ar += dpp_xor2(ar); ar += swz_xor4(ar);
    az += dpp_xor1(az); az += dpp_xor2(az); az += swz_xor4(az);
    an += dpp_xor1(an); an += dpp_xor2(an); an += swz_xor4(an);
    if (kh == 0) {
      float r = sigmoidf_(xr + ar + br);
      float z = sigmoidf_(xz + az + bz);
      float n = tanh_fast(xn + r * (an + bn2));
      float hnew = (1.f - z) * n + z * hprev;
      hprev = hnew;
      hbuf[cur ^ 1][jj] = (f16)hnew;
      hs_relu[(size_t)(b * 128 + t) * 128 + jj] = f2bf(fmaxf(hnew, 0.f));
    }
    __syncthreads();
    cur ^= 1;
  }
}

// ---------------- mean over timesteps ----------------
__global__ __launch_bounds__(256) void mean_k(const unsigned short* __restrict__ tf,
                                              const float* __restrict__ len_mask,
                                              float* __restrict__ mean,
                                              float* __restrict__ len_info){
  int b = blockIdx.x, c = threadIdx.x;
  float acc = 0.f;
  for (int s = 0; s < 128; s++) acc += bf2f(tf[(size_t)(b * 128 + s) * 256 + c]);
  float len = 0.f;
  for (int s = 0; s < 128; s++) len += len_mask[b * 128 + s];
  mean[b * 256 + c] = acc / len;
  if (c == 0) len_info[b] = len;
}

// ---------------- fused 3-token attention (thread per (n, head)) ----------------
__global__ __launch_bounds__(256) void attn_k(const unsigned short* __restrict__ qkv0,
                                              const unsigned short* __restrict__ qkv1,
                                              const unsigned short* __restrict__ qkv2,
                                              unsigned short* __restrict__ osum){
  int i = blockIdx.x * 256 + threadIdx.x;   // 32768
  int h = i & 1; int n = i >> 1; int b = n >> 7;
  const unsigned short* t0 = qkv0 + (size_t)b * 768 + h * 128;
  const unsigned short* t1 = qkv1 + (size_t)n * 768 + h * 128;
  const unsigned short* t2 = qkv2 + (size_t)n * 768 + h * 128;
  float sc[3][3];
  #pragma unroll
  for (int a = 0; a < 3; a++)
    #pragma unroll
    for (int s = 0; s < 3; s++) sc[a][s] = 0.f;
  #pragma unroll 1
  for (int dc = 0; dc < 16; dc++) {
    float q[3][8], k[3][8];
    load8bf(t0 + dc * 8, q[0]); load8bf(t1 + dc * 8, q[1]); load8bf(t2 + dc * 8, q[2]);
    load8bf(t0 + 256 + dc * 8, k[0]); load8bf(t1 + 256 + dc * 8, k[1]); load8bf(t2 + 256 + dc * 8, k[2]);
    #pragma unroll
    for (int a = 0; a < 3; a++)
      #pragma unroll
      for (int s = 0; s < 3; s++) {
        float d = 0.f;
        #pragma unroll
        for (int e = 0; e < 8; e++) d += q[a][e] * k[s][e];
        sc[a][s] += d;
      }
  }
  const float scale = 0.08838834764831845f;   // 1/sqrt(128)
  float w[3] = {0.f, 0.f, 0.f};
  #pragma unroll
  for (int a = 0; a < 3; a++) {
    float s0 = sc[a][0] * scale, s1 = sc[a][1] * scale, s2 = sc[a][2] * scale;
    float m = fmaxf(s0, fmaxf(s1, s2));
    float e0 = __expf(s0 - m), e1 = __expf(s1 - m), e2 = __expf(s2 - m);
    float inv = 1.f / (e0 + e1 + e2);
    w[0] += e0 * inv; w[1] += e1 * inv; w[2] += e2 * inv;
  }
  w[0] *= (1.f / 3.f); w[1] *= (1.f / 3.f); w[2] *= (1.f / 3.f);
  unsigned short* op = osum + (size_t)n * 256 + h * 128;
  #pragma unroll 1
  for (int dc = 0; dc < 16; dc++) {
    float v0[8], v1[8], v2[8];
    load8bf(t0 + 512 + dc * 8, v0); load8bf(t1 + 512 + dc * 8, v1); load8bf(t2 + 512 + dc * 8, v2);
    union { unsigned short s[8]; uint4 q; } u;
    #pragma unroll
    for (int e = 0; e < 8; e++) u.s[e] = f2bf(w[0] * v0[e] + w[1] * v1[e] + w[2] * v2[e]);
    *(uint4*)(op + dc * 8) = u.q;
  }
}

// ---------------- softmax-CE loss per row ----------------
__global__ __launch_bounds__(64) void loss_k(const float* __restrict__ logits,
                                             const float* __restrict__ label_mask,
                                             const int* __restrict__ labels,
                                             float* __restrict__ loss_raw){
  int r = blockIdx.x; int j = threadIdx.x;
  int lab = labels[r];
  float l[3]; float m = -1e30f;
  #pragma unroll
  for (int q = 0; q < 3; q++) {
    int c = j + q * 64;
    float lv = (c < 190) ? logits[(size_t)r * 192 + c] : -1e30f;
    l[q] = lv; m = fmaxf(m, lv);
  }
  #pragma unroll
  for (int off = 32; off; off >>= 1) m = fmaxf(m, __shfl_xor(m, off));
  float se = 0.f, soh = 0.f, dot = 0.f;
  #pragma unroll
  for (int q = 0; q < 3; q++) {
    int c = j + q * 64;
    if (c < 190) {
      se += expf(l[q] - m);
      float oh = fmaxf(label_mask[(size_t)r * 190 + c], (c == lab) ? 1.f : 0.f);
      soh += oh; dot += oh * l[q];
    }
  }
  #pragma unroll
  for (int off = 32; off; off >>= 1) {
    se += __shfl_xor(se, off); soh += __shfl_xor(soh, off); dot += __shfl_xor(dot, off);
  }
  if (j == 0) loss_raw[r] = (m + logf(se)) * soh - dot;
}

__global__ __launch_bounds__(256) void final_k(const float* __restrict__ loss_raw,
                                               const float* __restrict__ len_mask,
                                               const float* __restrict__ len_info,
                                               float* __restrict__ out){
  __shared__ float sh[256];
  int t = threadIdx.x;
  float acc = 0.f;
  for (int i = t; i < 16384; i += 256) acc += loss_raw[i] * len_mask[i] / len_info[i >> 7];
  sh[t] = acc; __syncthreads();
  for (int s = 128; s; s >>= 1) { if (t < s) sh[t] += sh[t + s]; __syncthreads(); }
  if (t == 0) out[0] = sh[0] / 128.f;
}

// ---------------- launch ----------------
extern "C" void kernel_launch(void* const* d_in, const int* in_sizes, int n_in,
                              void* d_out, int out_size, void* d_ws, size_t ws_size,
                              hipStream_t stream)
{
  const float* img_emb    = (const float*)d_in[0];
  const float* text_embs  = (const float*)d_in[1];
  const float* len_mask   = (const float*)d_in[2];
  const float* label_mask = (const float*)d_in[3];
  const int*   labels     = (const int*)  d_in[4];
  const float* img_W   = (const float*)d_in[5];
  const float* img_b   = (const float*)d_in[6];
  const float* img_g   = (const float*)d_in[7];
  const float* img_be  = (const float*)d_in[8];
  const float* img_m   = (const float*)d_in[9];
  const float* img_v   = (const float*)d_in[10];
  const float* g1_Wih  = (const float*)d_in[11];
  const float* g1_Whh  = (const float*)d_in[12];
  const float* g1_bih  = (const float*)d_in[13];
  const float* g1_bhh  = (const float*)d_in[14];
  const float* tl_W    = (const float*)d_in[15];
  const float* tl_b    = (const float*)d_in[16];
  const float* t_g     = (const float*)d_in[17];
  const float* t_be    = (const float*)d_in[18];
  const float* t_m     = (const float*)d_in[19];
  const float* t_v     = (const float*)d_in[20];
  const float* g2_Wih  = (const float*)d_in[21];
  const float* g2_Whh  = (const float*)d_in[22];
  const float* g2_bih  = (const float*)d_in[23];
  const float* g2_bhh  = (const float*)d_in[24];
  const float* cl_W    = (const float*)d_in[25];
  const float* cl_b    = (const float*)d_in[26];
  const float* c_g     = (const float*)d_in[27];
  const float* c_be    = (const float*)d_in[28];
  const float* c_m     = (const float*)d_in[29];
  const float* c_v     = (const float*)d_in[30];
  const float* a_Win   = (const float*)d_in[31];
  const float* a_bin   = (const float*)d_in[32];
  const float* a_Wout  = (const float*)d_in[33];
  const float* a_bout  = (const float*)d_in[34];
  const float* pred_W  = (const float*)d_in[35];
  const float* pred_b  = (const float*)d_in[36];

  char* ws = (char*)d_ws;
  size_t o = 0;
  auto alloc = [&](size_t sz){ size_t r = o; o += (sz + 255) & ~(size_t)255; return r; };

  // bf16 weight copies
  size_t o_g1Wih = alloc(384ull*2048*2);
  size_t o_tlW   = alloc(256ull*128*2);
  size_t o_g2Wih = alloc(768ull*256*2);
  size_t o_g2Whh = alloc(768ull*256*2);      // f16 copy for gru2
  size_t o_clW   = alloc(256ull*256*2);
  size_t o_aWin  = alloc(768ull*256*2);
  size_t o_aWout = alloc(256ull*256*2);
  size_t o_imgW  = alloc(256ull*2048*2);
  size_t o_predW = alloc(192ull*256*2);
  size_t o_predb = alloc(192ull*4);
  size_t o_imgfea= alloc(128ull*256*2);      // bf16
  size_t o_mean  = alloc(128ull*256*4);
  size_t o_len   = alloc(128ull*4);
  size_t o_R0    = alloc(33554432ull);        // xp2(f16)@+0, hs2(bf16)@+25165824 ; later osum@+0, last@+8388608
  size_t o_RB    = alloc(25165824ull);        // xp1(f16)@+0, hs1@+12582912 ; later qkv2@+0
  size_t o_tfea  = alloc(16384ull*256*2);     // text_fea bf16
  size_t o_qkv1  = alloc(16384ull*768*2);     // later logits (f32 [16384][192]) @ +0
  size_t o_cfea  = alloc(16384ull*256*2);
  size_t o_qkv0  = alloc(128ull*768*2);
  size_t o_loss  = alloc(16384ull*4);
  (void)ws_size; (void)in_sizes; (void)n_in; (void)out_size;

  unsigned short* g1Wih_bf = (unsigned short*)(ws + o_g1Wih);
  unsigned short* tlW_bf   = (unsigned short*)(ws + o_tlW);
  unsigned short* g2Wih_bf = (unsigned short*)(ws + o_g2Wih);
  f16*            g2Whh_f  = (f16*)(ws + o_g2Whh);
  unsigned short* clW_bf   = (unsigned short*)(ws + o_clW);
  unsigned short* aWin_bf  = (unsigned short*)(ws + o_aWin);
  unsigned short* aWout_bf = (unsigned short*)(ws + o_aWout);
  unsigned short* imgW_bf  = (unsigned short*)(ws + o_imgW);
  unsigned short* predW_bf = (unsigned short*)(ws + o_predW);
  float*          predb_p  = (float*)(ws + o_predb);
  unsigned short* img_fea  = (unsigned short*)(ws + o_imgfea);
  float*          meanb    = (float*)(ws + o_mean);
  float*          len_info = (float*)(ws + o_len);
  f16*            xp2      = (f16*)(ws + o_R0);
  unsigned short* hs2      = (unsigned short*)(ws + o_R0 + 25165824ull);
  unsigned short* osum     = (unsigned short*)(ws + o_R0);
  unsigned short* lastb    = (unsigned short*)(ws + o_R0 + 8388608ull);
  f16*            xp1      = (f16*)(ws + o_RB);
  unsigned short* hs1      = (unsigned short*)(ws + o_RB + 12582912ull);
  unsigned short* qkv2     = (unsigned short*)(ws + o_RB);
  unsigned short* tfea     = (unsigned short*)(ws + o_tfea);
  unsigned short* qkv1     = (unsigned short*)(ws + o_qkv1);
  float*          logits   = (float*)(ws + o_qkv1);
  unsigned short* cfea     = (unsigned short*)(ws + o_cfea);
  unsigned short* qkv0     = (unsigned short*)(ws + o_qkv0);
  float*          loss_raw = (float*)(ws + o_loss);
  float*          outp     = (float*)d_out;

  // one fused weight-conversion launch (8 segments)
  conv_all_k<<<2016, 256, 0, stream>>>(
      g1_Wih, tl_W, g2_Wih, g2_Whh, cl_W, a_Win, a_Wout, img_W,
      g1Wih_bf, tlW_bf, g2Wih_bf, g2Whh_f, clW_bf, aWin_bf, aWout_bf, imgW_bf);
  pred_pad_k<<<192, 256, 0, stream>>>(pred_W, pred_b, predW_bf, predb_p);

  // img encoder: Linear + BN + ReLU  -> img_fea (bf16)
  gemm128_k<2, true, 1><<<dim3(2, 1), 256, 0, stream>>>(
      img_emb, imgW_bf, img_b, img_g, img_be, img_m, img_v, img_fea, 128, 256, 2048);

  // xp1 = text_embs @ g1_Wih^T + bih  -> f16
  gemm128_k<1, false, 1><<<dim3(3, 128), 256, 0, stream>>>(
      text_embs, g1Wih_bf, g1_bih, nullptr, nullptr, nullptr, nullptr, xp1, 16384, 384, 2048);

  // GRU1 scan -> relu(h) bf16  (1024 threads, 4 waves/SIMD)
  gru1_scan_k<<<128, 1024, 0, stream>>>(g1_Whh, g1_bhh, xp1, hs1);

  // tl: Linear + BN + ReLU -> text_fea
  gemm128_k<2, true, 0><<<dim3(2, 128), 256, 0, stream>>>(
      hs1, tlW_bf, tl_b, t_g, t_be, t_m, t_v, tfea, 16384, 256, 128);

  // mean over timesteps (contrast folded into xp2 staging)
  mean_k<<<128, 256, 0, stream>>>(tfea, len_mask, meanb, len_info);

  // xp2 = (tfea - mean) @ g2_Wih^T + bih   (A_MODE=2: subtract mean during staging)
  gemm128_k<1, false, 2><<<dim3(6, 128), 256, 0, stream>>>(
      tfea, g2Wih_bf, g2_bih, nullptr, nullptr, meanb, nullptr, xp2, 16384, 768, 256);

  // GRU2 scan (r in regs; z,n streamed from L2; h only in LDS)
  gru2_scan_k<<<128, 512, 0, stream>>>(g2Whh_f, g2_bhh, xp2, hs2);

  // cl: Linear + BN + ReLU -> contrast_fea
  gemm128_k<2, true, 0><<<dim3(2, 128), 256, 0, stream>>>(
      hs2, clW_bf, cl_b, c_g, c_be, c_m, c_v, cfea, 16384, 256, 256);

  // qkv projections for the 3 tokens
  gemm128_k<2, false, 0><<<dim3(6, 1), 256, 0, stream>>>(
      img_fea, aWin_bf, a_bin, nullptr, nullptr, nullptr, nullptr, qkv0, 128, 768, 256);
  gemm128_k<2, false, 0><<<dim3(6, 128), 256, 0, stream>>>(
      tfea, aWin_bf, a_bin, nullptr, nullptr, nullptr, nullptr, qkv1, 16384, 768, 256);
  gemm128_k<2, false, 0><<<dim3(6, 128), 256, 0, stream>>>(
      cfea, aWin_bf, a_bin, nullptr, nullptr, nullptr, nullptr, qkv2, 16384, 768, 256);

  // fused 3x3 attention -> mean over tokens (pre-projection)
  attn_k<<<128, 256, 0, stream>>>(qkv0, qkv1, qkv2, osum);

  // output projection (applied to token-mean; linearity) -> last
  gemm128_k<2, false, 0><<<dim3(2, 128), 256, 0, stream>>>(
      osum, aWout_bf, a_bout, nullptr, nullptr, nullptr, nullptr, lastb, 16384, 256, 256);

  // logits (N padded to 192) — 64-tile kernel
  gemm_k<0, false, false><<<dim3(3, 256), 256, 0, stream>>>(
      lastb, predW_bf, predb_p, nullptr, nullptr, nullptr, nullptr, logits, 16384, 192, 256);

  // per-row CE loss, then masked mean
  loss_k<<<16384, 64, 0, stream>>>(logits, label_mask, labels, loss_raw);
  final_k<<<1, 256, 0, stream>>>(loss_raw, len_mask, len_info, outp);
}

// Round 17
// 597.363 us; speedup vs baseline: 1.0806x; 1.0806x over previous
//
#include <hip/hip_runtime.h>

// ---------------- types & helpers ----------------
typedef __attribute__((ext_vector_type(8))) short short8;   // 8 bf16 (4 VGPR)
typedef __attribute__((ext_vector_type(4))) float f32x4;
typedef _Float16 f16;
typedef __attribute__((ext_vector_type(2))) _Float16 f16x2;
typedef __attribute__((ext_vector_type(8))) _Float16 f16x8;

__device__ inline float bf2f(unsigned short u){
  union{float f; unsigned u32;} x; x.u32 = ((unsigned)u) << 16; return x.f;
}
__device__ inline unsigned short f2bf(float f){
  union{float f; unsigned u;} x; x.f = f;
  unsigned r = (x.u + 0x7FFFu + ((x.u >> 16) & 1u)) >> 16;
  return (unsigned short)r;
}

#if defined(__has_builtin)
#  if __has_builtin(__builtin_amdgcn_fdot2)
#    define HAS_FDOT2 1
#  endif
#endif
__device__ inline float dot2f(f16x2 a, f16x2 b, float c){
#ifdef HAS_FDOT2
  return __builtin_amdgcn_fdot2(a, b, c, false);
#else
  return c + (float)a.x * (float)b.x + (float)a.y * (float)b.y;
#endif
}
__device__ inline f16x2 asf16x2(int v){ return __builtin_bit_cast(f16x2, v); }
__device__ inline int pack2(float lo, float hi){
  f16x2 p = f16x2{(f16)lo, (f16)hi};
  return __builtin_bit_cast(int, p);
}

__device__ inline float sigmoidf_(float x){ return 1.f / (1.f + __expf(-x)); }
__device__ inline float tanh_fast(float x){ float e = __expf(2.f * x); return 1.f - 2.f / (e + 1.f); }

// DPP quad-permute butterfly adds (VALU pipe)
__device__ inline float dpp_xor1(float x){
  return __int_as_float(__builtin_amdgcn_update_dpp(0, __float_as_int(x), 0xB1, 0xF, 0xF, true));
}
__device__ inline float dpp_xor2(float x){
  return __int_as_float(__builtin_amdgcn_update_dpp(0, __float_as_int(x), 0x4E, 0xF, 0xF, true));
}

__device__ inline void load8bf(const unsigned short* p, float* o){
  uint4 q = *(const uint4*)p;
  o[0]=bf2f((unsigned short)(q.x & 0xffffu)); o[1]=bf2f((unsigned short)(q.x >> 16));
  o[2]=bf2f((unsigned short)(q.y & 0xffffu)); o[3]=bf2f((unsigned short)(q.y >> 16));
  o[4]=bf2f((unsigned short)(q.z & 0xffffu)); o[5]=bf2f((unsigned short)(q.z >> 16));
  o[6]=bf2f((unsigned short)(q.w & 0xffffu)); o[7]=bf2f((unsigned short)(q.w >> 16));
}

// async global->LDS, 16 bytes per lane (lds dest = wave-uniform base + lane*16)
#define GLL16(g, l) __builtin_amdgcn_global_load_lds(                      \
    (const __attribute__((address_space(1))) void*)(g),                    \
    (__attribute__((address_space(3))) void*)(l), 16, 0, 0)

// ---------------- fused weight conversion (8 segments, one launch) ----------------
__global__ __launch_bounds__(256) void conv_all_k(
    const float* __restrict__ s0, const float* __restrict__ s1,
    const float* __restrict__ s2, const float* __restrict__ s3,
    const float* __restrict__ s4, const float* __restrict__ s5,
    const float* __restrict__ s6, const float* __restrict__ s7,
    unsigned short* __restrict__ d0, unsigned short* __restrict__ d1,
    unsigned short* __restrict__ d2, f16* __restrict__ d3,
    unsigned short* __restrict__ d4, unsigned short* __restrict__ d5,
    unsigned short* __restrict__ d6, unsigned short* __restrict__ d7)
{
  int i = blockIdx.x * 256 + threadIdx.x;
  if (i >= 516096) return;
  const float* src; int local; int mode = 0; unsigned short* dst = nullptr; f16* dstf = nullptr;
  if (i < 196608)      { src = s0; local = i;           dst = d0; }
  else if (i < 204800) { src = s1; local = i - 196608;  dst = d1; }
  else if (i < 253952) { src = s2; local = i - 204800;  dst = d2; }
  else if (i < 303104) { src = s3; local = i - 253952;  dstf = d3; mode = 1; }
  else if (i < 319488) { src = s4; local = i - 303104;  dst = d4; }
  else if (i < 368640) { src = s5; local = i - 319488;  dst = d5; }
  else if (i < 385024) { src = s6; local = i - 368640;  dst = d6; }
  else                 { src = s7; local = i - 385024;  dst = d7; }
  float4 v = ((const float4*)src)[local];
  if (mode == 0) {
    union { unsigned short s[4]; uint2 q; } u;
    u.s[0]=f2bf(v.x); u.s[1]=f2bf(v.y); u.s[2]=f2bf(v.z); u.s[3]=f2bf(v.w);
    ((uint2*)dst)[local] = u.q;
  } else {
    union { f16 s[4]; uint2 q; } u;
    u.s[0]=(f16)v.x; u.s[1]=(f16)v.y; u.s[2]=(f16)v.z; u.s[3]=(f16)v.w;
    ((uint2*)dstf)[local] = u.q;
  }
}

// pred_W [190][256] -> [192][256] zero-padded bf16; pred_b -> [192] zero-padded f32
__global__ __launch_bounds__(256) void pred_pad_k(const float* __restrict__ W,
                                                  const float* __restrict__ b,
                                                  unsigned short* __restrict__ Wd,
                                                  float* __restrict__ bd){
  int i = blockIdx.x * 256 + threadIdx.x;   // 192*256 threads
  int j = i >> 8;
  Wd[i] = (j < 190) ? f2bf(W[i]) : (unsigned short)0;
  if (i < 192) bd[i] = (i < 190) ? b[i] : 0.f;
}

// ---------------- 128x128-tile MFMA GEMM (m97 structure) ----------------
// A_MODE: 0 = bf16 via global_load_lds; 1 = f32 reg-convert; 2 = bf16 minus mean.
template<int OUT_T, bool BN, int A_MODE>
__global__ __launch_bounds__(256) void gemm128_k(
    const void* __restrict__ Ap, const unsigned short* __restrict__ Bw,
    const float* __restrict__ bias,
    const float* __restrict__ gam, const float* __restrict__ bet,
    const float* __restrict__ mu,  const float* __restrict__ var,
    void* __restrict__ Cp, int M, int N, int K)
{
  __shared__ __align__(16) unsigned short As[4096];   // [128][32]
  __shared__ __align__(16) unsigned short Bs[4096];
  const int tid  = threadIdx.x;
  const int lane = tid & 63, wid = tid >> 6;
  const int wm = wid & 1, wn = wid >> 1;
  const int bm = blockIdx.y << 7, bn = blockIdx.x << 7;
  const int rA = tid >> 2, seg = tid & 3;

  f32x4 acc[4][4];
  #pragma unroll
  for (int i = 0; i < 4; i++)
    #pragma unroll
    for (int j = 0; j < 4; j++)
      acc[i][j] = f32x4{0.f, 0.f, 0.f, 0.f};

  const unsigned short* Abf = (const unsigned short*)Ap;
  const float* Af = (const float*)Ap;
  char* asb = (char*)As;
  char* bsb = (char*)Bs;
  char* asw = asb + wid * 1024;
  char* bsw = bsb + wid * 1024;

  for (int k0 = 0; k0 < K; k0 += 32) {
    if (A_MODE == 1) {
      #pragma unroll
      for (int beta = 0; beta < 2; beta++) {
        const float* src = Af + (size_t)(bm + rA + beta * 64) * K + k0 + seg * 8;
        float4 v0 = *(const float4*)src;
        float4 v1 = *(const float4*)(src + 4);
        union { unsigned short s[8]; uint4 q; } u;
        u.s[0]=f2bf(v0.x); u.s[1]=f2bf(v0.y); u.s[2]=f2bf(v0.z); u.s[3]=f2bf(v0.w);
        u.s[4]=f2bf(v1.x); u.s[5]=f2bf(v1.y); u.s[6]=f2bf(v1.z); u.s[7]=f2bf(v1.w);
        *(uint4*)(asb + beta * 4096 + tid * 16) = u.q;
      }
    } else if (A_MODE == 2) {
      const float* mrow = mu + (size_t)(bm >> 7) * 256 + k0 + seg * 8;
      float4 m0 = *(const float4*)mrow;
      float4 m1 = *(const float4*)(mrow + 4);
      #pragma unroll
      for (int beta = 0; beta < 2; beta++) {
        const unsigned short* src = Abf + (size_t)(bm + rA + beta * 64) * K + k0 + seg * 8;
        float av[8];
        load8bf(src, av);
        union { unsigned short s[8]; uint4 q; } u;
        u.s[0]=f2bf(av[0]-m0.x); u.s[1]=f2bf(av[1]-m0.y); u.s[2]=f2bf(av[2]-m0.z); u.s[3]=f2bf(av[3]-m0.w);
        u.s[4]=f2bf(av[4]-m1.x); u.s[5]=f2bf(av[5]-m1.y); u.s[6]=f2bf(av[6]-m1.z); u.s[7]=f2bf(av[7]-m1.w);
        *(uint4*)(asb + beta * 4096 + tid * 16) = u.q;
      }
    } else {
      GLL16(Abf + (size_t)(bm + rA)      * K + k0 + seg * 8, asw);
      GLL16(Abf + (size_t)(bm + rA + 64) * K + k0 + seg * 8, asw + 4096);
    }
    GLL16(Bw + (size_t)(bn + rA)      * K + k0 + seg * 8, bsw);
    GLL16(Bw + (size_t)(bn + rA + 64) * K + k0 + seg * 8, bsw + 4096);
    __syncthreads();

    short8 a[4], b[4];
    #pragma unroll
    for (int f = 0; f < 4; f++) {
      int ra = wm * 64 + f * 16 + (lane & 15);
      a[f] = *(const short8*)(asb + ra * 64 + (lane >> 4) * 16);
      int rb = wn * 64 + f * 16 + (lane & 15);
      b[f] = *(const short8*)(bsb + rb * 64 + (lane >> 4) * 16);
    }
    #pragma unroll
    for (int fm = 0; fm < 4; fm++)
      #pragma unroll
      for (int fn = 0; fn < 4; fn++)
        acc[fm][fn] = __builtin_amdgcn_mfma_f32_16x16x32_bf16(a[fm], b[fn], acc[fm][fn], 0, 0, 0);
    __syncthreads();
  }

  #pragma unroll
  for (int fn = 0; fn < 4; fn++) {
    int col = bn + wn * 64 + fn * 16 + (lane & 15);
    float bs = bias[col];
    float sc = 1.f, sh = 0.f;
    if (BN) { float s = gam[col] * rsqrtf(var[col] + 1e-5f); sc = s; sh = bet[col] - mu[col] * s; }
    #pragma unroll
    for (int fm = 0; fm < 4; fm++) {
      int row = bm + wm * 64 + fm * 16 + ((lane >> 4) << 2);
      #pragma unroll
      for (int j = 0; j < 4; j++) {
        float v = acc[fm][fn][j] + bs;
        if (BN) { v = v * sc + sh; v = fmaxf(v, 0.f); }
        size_t idx = (size_t)(row + j) * N + col;
        if (OUT_T == 1) ((f16*)Cp)[idx] = (f16)v;
        else            ((unsigned short*)Cp)[idx] = f2bf(v);
      }
    }
  }
}

// ---------------- 64-tile MFMA GEMM (kept for logits, N=192) ----------------
template<int OUT_T, bool BN, bool AF32>
__global__ __launch_bounds__(256) void gemm_k(
    const void* __restrict__ Ap, const unsigned short* __restrict__ Bw,
    const float* __restrict__ bias,
    const float* __restrict__ gam, const float* __restrict__ bet,
    const float* __restrict__ mu,  const float* __restrict__ var,
    void* __restrict__ Cp, int M, int N, int K)
{
  __shared__ unsigned short As[64][40];
  __shared__ unsigned short Bs[64][40];
  const int tid  = threadIdx.x;
  const int lane = tid & 63, wid = tid >> 6;
  const int wm = wid & 1, wn = wid >> 1;
  const int bm = blockIdx.y << 6, bn = blockIdx.x << 6;
  const int srow = tid >> 2, sseg = tid & 3;

  f32x4 acc[2][2];
  #pragma unroll
  for (int i = 0; i < 2; i++)
    #pragma unroll
    for (int j = 0; j < 2; j++)
      acc[i][j] = f32x4{0.f, 0.f, 0.f, 0.f};

  const unsigned short* Abf = (const unsigned short*)Ap;
  const float* Af = (const float*)Ap;

  for (int k0 = 0; k0 < K; k0 += 32) {
    if (AF32) {
      const float* src = Af + (size_t)(bm + srow) * K + k0 + sseg * 8;
      float4 v0 = *(const float4*)(src);
      float4 v1 = *(const float4*)(src + 4);
      union { unsigned short s[8]; uint4 q; } u;
      u.s[0]=f2bf(v0.x); u.s[1]=f2bf(v0.y); u.s[2]=f2bf(v0.z); u.s[3]=f2bf(v0.w);
      u.s[4]=f2bf(v1.x); u.s[5]=f2bf(v1.y); u.s[6]=f2bf(v1.z); u.s[7]=f2bf(v1.w);
      *(uint4*)&As[srow][sseg * 8] = u.q;
    } else {
      *(uint4*)&As[srow][sseg * 8] =
          *(const uint4*)(Abf + (size_t)(bm + srow) * K + k0 + sseg * 8);
    }
    *(uint4*)&Bs[srow][sseg * 8] =
        *(const uint4*)(Bw + (size_t)(bn + srow) * K + k0 + sseg * 8);
    __syncthreads();

    short8 a0 = *(const short8*)&As[wm * 32 +      (lane & 15)][(lane >> 4) * 8];
    short8 a1 = *(const short8*)&As[wm * 32 + 16 + (lane & 15)][(lane >> 4) * 8];
    short8 b0 = *(const short8*)&Bs[wn * 32 +      (lane & 15)][(lane >> 4) * 8];
    short8 b1 = *(const short8*)&Bs[wn * 32 + 16 + (lane & 15)][(lane >> 4) * 8];
    acc[0][0] = __builtin_amdgcn_mfma_f32_16x16x32_bf16(a0, b0, acc[0][0], 0, 0, 0);
    acc[0][1] = __builtin_amdgcn_mfma_f32_16x16x32_bf16(a0, b1, acc[0][1], 0, 0, 0);
    acc[1][0] = __builtin_amdgcn_mfma_f32_16x16x32_bf16(a1, b0, acc[1][0], 0, 0, 0);
    acc[1][1] = __builtin_amdgcn_mfma_f32_16x16x32_bf16(a1, b1, acc[1][1], 0, 0, 0);
    __syncthreads();
  }

  #pragma unroll
  for (int fn = 0; fn < 2; fn++) {
    int col = bn + wn * 32 + fn * 16 + (lane & 15);
    float bs = bias[col];
    float sc = 1.f, sh = 0.f;
    if (BN) { float s = gam[col] * rsqrtf(var[col] + 1e-5f); sc = s; sh = bet[col] - mu[col] * s; }
    #pragma unroll
    for (int fm = 0; fm < 2; fm++) {
      int row = bm + wm * 32 + fm * 16 + ((lane >> 4) << 2);
      #pragma unroll
      for (int j = 0; j < 4; j++) {
        float v = acc[fm][fn][j] + bs;
        if (BN) { v = v * sc + sh; v = fmaxf(v, 0.f); }
        size_t idx = (size_t)(row + j) * N + col;
        if (OUT_T == 0)      ((float*)Cp)[idx] = v;
        else if (OUT_T == 1) ((f16*)Cp)[idx]   = (f16)v;
        else                 ((unsigned short*)Cp)[idx] = f2bf(v);
      }
    }
  }
}

// ---------------- GRU scans ----------------
// GRU2 (LDS-minimal, round-16 best): 512 threads, jj = tid>>1, kh = tid&1.
// Gate r: 64 opaque VGPRs. Gates z,n: streamed from L2 every step via 4-deep
// rolling uint4 buffers. LDS = 16 broadcast h reads + 1 h write per thread/step.
__global__ __launch_bounds__(512, 2) void gru2_scan_k(
    const f16* __restrict__ Wf,              // [768][256] f16
    const float* __restrict__ bhh,
    const f16* __restrict__ xp, unsigned short* __restrict__ hs_relu)
{
  const int b = blockIdx.x;
  const int tid = threadIdx.x;
  const int jj = tid >> 1, kh = tid & 1;
  __shared__ __align__(16) f16 hbuf[2][256];

  int wri[64];
  #pragma unroll
  for (int i = 0; i < 16; i++) {
    uint4 q = *(const uint4*)&Wf[(size_t)jj * 256 + kh * 128 + i * 8];
    wri[4*i+0] = (int)q.x; wri[4*i+1] = (int)q.y; wri[4*i+2] = (int)q.z; wri[4*i+3] = (int)q.w;
  }
  #pragma unroll
  for (int i = 0; i < 64; i++)
    asm volatile("" : "+v"(wri[i]));

  const f16* zsrc = Wf + (size_t)(256 + jj) * 256 + kh * 128;
  const f16* nsrc = Wf + (size_t)(512 + jj) * 256 + kh * 128;

  const float br = bhh[jj], bz = bhh[jj + 256], bn2 = bhh[jj + 512];
  if (tid < 256) hbuf[0][tid] = (f16)0.f;
  float hprev = 0.f;
  f16 pxr = (f16)0.f, pxz = (f16)0.f, pxn = (f16)0.f;
  if (kh == 0) {
    const f16* x0 = xp + (size_t)(b * 128) * 768;
    pxr = x0[jj]; pxz = x0[256 + jj]; pxn = x0[512 + jj];
  }
  __syncthreads();
  int cur = 0;
  for (int t = 0; t < 128; t++) {
    float xr = (float)pxr, xz = (float)pxz, xn = (float)pxn;
    if (kh == 0) {
      const int tn = (t < 127) ? (t + 1) : 127;
      const f16* xnr = xp + (size_t)(b * 128 + tn) * 768;
      pxr = xnr[jj]; pxz = xnr[256 + jj]; pxn = xnr[512 + jj];
    }
    uint4 zb[4], nb[4];
    #pragma unroll
    for (int c = 0; c < 4; c++) {
      zb[c] = *(const uint4*)(zsrc + c * 8);
      nb[c] = *(const uint4*)(nsrc + c * 8);
    }
    const char* hb = (const char*)hbuf[cur] + kh * 256;
    float ar = 0.f, az = 0.f, an = 0.f;
    #pragma unroll
    for (int i = 0; i < 16; i++) {
      f16x8 hv = *(const f16x8*)(hb + i * 16);
      f16x8 zv = __builtin_bit_cast(f16x8, zb[i & 3]);
      f16x8 nv = __builtin_bit_cast(f16x8, nb[i & 3]);
      if (i < 12) {
        zb[i & 3] = *(const uint4*)(zsrc + (i + 4) * 8);
        nb[i & 3] = *(const uint4*)(nsrc + (i + 4) * 8);
      }
      #pragma unroll
      for (int u = 0; u < 4; u++) {
        f16x2 hp = f16x2{hv[2*u], hv[2*u+1]};
        ar = dot2f(asf16x2(wri[4*i+u]), hp, ar);
        az = dot2f(f16x2{zv[2*u], zv[2*u+1]}, hp, az);
        an = dot2f(f16x2{nv[2*u], nv[2*u+1]}, hp, an);
      }
    }
    ar += dpp_xor1(ar);
    az += dpp_xor1(az);
    an += dpp_xor1(an);
    if (kh == 0) {
      float r = sigmoidf_(xr + ar + br);
      float z = sigmoidf_(xz + az + bz);
      float n = tanh_fast(xn + r * (an + bn2));
      float hnew = (1.f - z) * n + z * hprev;
      hprev = hnew;
      hbuf[cur ^ 1][jj] = (f16)hnew;
      hs_relu[(size_t)(b * 128 + t) * 256 + jj] = f2bf(fmaxf(hnew, 0.f));
    }
    __syncthreads();
    cur ^= 1;
  }
}

// GRU1 (round-15 best): H=128, gates 384. 512 thr: jj = tid>>2, kh = tid&3.
__global__ __launch_bounds__(512, 4) void gru1_scan_k(
    const float* __restrict__ Whh, const float* __restrict__ bhh,
    const f16* __restrict__ xp, unsigned short* __restrict__ hs_relu)
{
  const int b = blockIdx.x;
  const int tid = threadIdx.x;
  const int jj = tid >> 2, kh = tid & 3;
  __shared__ __align__(16) f16 hbuf[2][128];

  int wri[16], wzi[16], wni[16];
  #pragma unroll
  for (int i = 0; i < 4; i++) {
    const int kb = kh * 32 + i * 8;
    float4 f0, f1;
    f0 = *(const float4*)&Whh[(size_t)(jj      ) * 128 + kb];
    f1 = *(const float4*)&Whh[(size_t)(jj      ) * 128 + kb + 4];
    wri[4*i+0] = pack2(f0.x, f0.y); wri[4*i+1] = pack2(f0.z, f0.w);
    wri[4*i+2] = pack2(f1.x, f1.y); wri[4*i+3] = pack2(f1.z, f1.w);
    f0 = *(const float4*)&Whh[(size_t)(jj + 128) * 128 + kb];
    f1 = *(const float4*)&Whh[(size_t)(jj + 128) * 128 + kb + 4];
    wzi[4*i+0] = pack2(f0.x, f0.y); wzi[4*i+1] = pack2(f0.z, f0.w);
    wzi[4*i+2] = pack2(f1.x, f1.y); wzi[4*i+3] = pack2(f1.z, f1.w);
    f0 = *(const float4*)&Whh[(size_t)(jj + 256) * 128 + kb];
    f1 = *(const float4*)&Whh[(size_t)(jj + 256) * 128 + kb + 4];
    wni[4*i+0] = pack2(f0.x, f0.y); wni[4*i+1] = pack2(f0.z, f0.w);
    wni[4*i+2] = pack2(f1.x, f1.y); wni[4*i+3] = pack2(f1.z, f1.w);
  }
  #pragma unroll
  for (int i = 0; i < 16; i++)
    asm volatile("" : "+v"(wri[i]), "+v"(wzi[i]), "+v"(wni[i]));

  const float br = bhh[jj], bz = bhh[jj + 128], bn2 = bhh[jj + 256];
  if (tid < 128) hbuf[0][tid] = (f16)0.f;
  float hprev = 0.f;
  f16 pxr = (f16)0.f, pxz = (f16)0.f, pxn = (f16)0.f;
  if (kh == 0) {
    const f16* x0 = xp + (size_t)(b * 128) * 384;
    pxr = x0[jj]; pxz = x0[128 + jj]; pxn = x0[256 + jj];
  }
  __syncthreads();
  int cur = 0;
  for (int t = 0; t < 128; t++) {
    float xr = (float)pxr, xz = (float)pxz, xn = (float)pxn;
    if (kh == 0) {
      const int tn = (t < 127) ? (t + 1) : 127;
      const f16* xnr = xp + (size_t)(b * 128 + tn) * 384;
      pxr = xnr[jj]; pxz = xnr[128 + jj]; pxn = xnr[256 + jj];
    }
    const char* hb = (const char*)hbuf[cur] + kh * 64;
    float ar = 0.f, az = 0.f, an = 0.f;
    #pragma unroll
    for (int c = 0; c < 4; c++) {
      f16x8 hv = *(const f16x8*)(hb + c * 16);
      #pragma unroll
      for (int u = 0; u < 4; u++) {
        f16x2 hp = f16x2{hv[2*u], hv[2*u+1]};
        ar = dot2f(asf16x2(wri[4*c+u]), hp, ar);
        az = dot2f(asf16x2(wzi[4*c+u]), hp, az);
        an = dot2f(asf16x2(wni[4*c+u]), hp, an);
      }
    }
    ar += dpp_xor1(ar); ar += dpp_xor2(ar);
    az += dpp_xor1(az); az += dpp_xor2(az);
    an += dpp_xor1(an); an += dpp_xor2(an);
    if (kh == 0) {
      float r = sigmoidf_(xr + ar + br);
      float z = sigmoidf_(xz + az + bz);
      float n = tanh_fast(xn + r * (an + bn2));
      float hnew = (1.f - z) * n + z * hprev;
      hprev = hnew;
      hbuf[cur ^ 1][jj] = (f16)hnew;
      hs_relu[(size_t)(b * 128 + t) * 128 + jj] = f2bf(fmaxf(hnew, 0.f));
    }
    __syncthreads();
    cur ^= 1;
  }
}

// ---------------- mean over timesteps ----------------
__global__ __launch_bounds__(256) void mean_k(const unsigned short* __restrict__ tf,
                                              const float* __restrict__ len_mask,
                                              float* __restrict__ mean,
                                              float* __restrict__ len_info){
  int b = blockIdx.x, c = threadIdx.x;
  float acc = 0.f;
  for (int s = 0; s < 128; s++) acc += bf2f(tf[(size_t)(b * 128 + s) * 256 + c]);
  float len = 0.f;
  for (int s = 0; s < 128; s++) len += len_mask[b * 128 + s];
  mean[b * 256 + c] = acc / len;
  if (c == 0) len_info[b] = len;
}

// ---------------- fused 3-token attention (thread per (n, head)) ----------------
__global__ __launch_bounds__(256) void attn_k(const unsigned short* __restrict__ qkv0,
                                              const unsigned short* __restrict__ qkv1,
                                              const unsigned short* __restrict__ qkv2,
                                              unsigned short* __restrict__ osum){
  int i = blockIdx.x * 256 + threadIdx.x;   // 32768
  int h = i & 1; int n = i >> 1; int b = n >> 7;
  const unsigned short* t0 = qkv0 + (size_t)b * 768 + h * 128;
  const unsigned short* t1 = qkv1 + (size_t)n * 768 + h * 128;
  const unsigned short* t2 = qkv2 + (size_t)n * 768 + h * 128;
  float sc[3][3];
  #pragma unroll
  for (int a = 0; a < 3; a++)
    #pragma unroll
    for (int s = 0; s < 3; s++) sc[a][s] = 0.f;
  #pragma unroll 1
  for (int dc = 0; dc < 16; dc++) {
    float q[3][8], k[3][8];
    load8bf(t0 + dc * 8, q[0]); load8bf(t1 + dc * 8, q[1]); load8bf(t2 + dc * 8, q[2]);
    load8bf(t0 + 256 + dc * 8, k[0]); load8bf(t1 + 256 + dc * 8, k[1]); load8bf(t2 + 256 + dc * 8, k[2]);
    #pragma unroll
    for (int a = 0; a < 3; a++)
      #pragma unroll
      for (int s = 0; s < 3; s++) {
        float d = 0.f;
        #pragma unroll
        for (int e = 0; e < 8; e++) d += q[a][e] * k[s][e];
        sc[a][s] += d;
      }
  }
  const float scale = 0.08838834764831845f;   // 1/sqrt(128)
  float w[3] = {0.f, 0.f, 0.f};
  #pragma unroll
  for (int a = 0; a < 3; a++) {
    float s0 = sc[a][0] * scale, s1 = sc[a][1] * scale, s2 = sc[a][2] * scale;
    float m = fmaxf(s0, fmaxf(s1, s2));
    float e0 = __expf(s0 - m), e1 = __expf(s1 - m), e2 = __expf(s2 - m);
    float inv = 1.f / (e0 + e1 + e2);
    w[0] += e0 * inv; w[1] += e1 * inv; w[2] += e2 * inv;
  }
  w[0] *= (1.f / 3.f); w[1] *= (1.f / 3.f); w[2] *= (1.f / 3.f);
  unsigned short* op = osum + (size_t)n * 256 + h * 128;
  #pragma unroll 1
  for (int dc = 0; dc < 16; dc++) {
    float v0[8], v1[8], v2[8];
    load8bf(t0 + 512 + dc * 8, v0); load8bf(t1 + 512 + dc * 8, v1); load8bf(t2 + 512 + dc * 8, v2);
    union { unsigned short s[8]; uint4 q; } u;
    #pragma unroll
    for (int e = 0; e < 8; e++) u.s[e] = f2bf(w[0] * v0[e] + w[1] * v1[e] + w[2] * v2[e]);
    *(uint4*)(op + dc * 8) = u.q;
  }
}

// ---------------- softmax-CE loss per row ----------------
__global__ __launch_bounds__(64) void loss_k(const float* __restrict__ logits,
                                             const float* __restrict__ label_mask,
                                             const int* __restrict__ labels,
                                             float* __restrict__ loss_raw){
  int r = blockIdx.x; int j = threadIdx.x;
  int lab = labels[r];
  float l[3]; float m = -1e30f;
  #pragma unroll
  for (int q = 0; q < 3; q++) {
    int c = j + q * 64;
    float lv = (c < 190) ? logits[(size_t)r * 192 + c] : -1e30f;
    l[q] = lv; m = fmaxf(m, lv);
  }
  #pragma unroll
  for (int off = 32; off; off >>= 1) m = fmaxf(m, __shfl_xor(m, off));
  float se = 0.f, soh = 0.f, dot = 0.f;
  #pragma unroll
  for (int q = 0; q < 3; q++) {
    int c = j + q * 64;
    if (c < 190) {
      se += expf(l[q] - m);
      float oh = fmaxf(label_mask[(size_t)r * 190 + c], (c == lab) ? 1.f : 0.f);
      soh += oh; dot += oh * l[q];
    }
  }
  #pragma unroll
  for (int off = 32; off; off >>= 1) {
    se += __shfl_xor(se, off); soh += __shfl_xor(soh, off); dot += __shfl_xor(dot, off);
  }
  if (j == 0) loss_raw[r] = (m + logf(se)) * soh - dot;
}

__global__ __launch_bounds__(256) void final_k(const float* __restrict__ loss_raw,
                                               const float* __restrict__ len_mask,
                                               const float* __restrict__ len_info,
                                               float* __restrict__ out){
  __shared__ float sh[256];
  int t = threadIdx.x;
  float acc = 0.f;
  for (int i = t; i < 16384; i += 256) acc += loss_raw[i] * len_mask[i] / len_info[i >> 7];
  sh[t] = acc; __syncthreads();
  for (int s = 128; s; s >>= 1) { if (t < s) sh[t] += sh[t + s]; __syncthreads(); }
  if (t == 0) out[0] = sh[0] / 128.f;
}

// ---------------- launch ----------------
extern "C" void kernel_launch(void* const* d_in, const int* in_sizes, int n_in,
                              void* d_out, int out_size, void* d_ws, size_t ws_size,
                              hipStream_t stream)
{
  const float* img_emb    = (const float*)d_in[0];
  const float* text_embs  = (const float*)d_in[1];
  const float* len_mask   = (const float*)d_in[2];
  const float* label_mask = (const float*)d_in[3];
  const int*   labels     = (const int*)  d_in[4];
  const float* img_W   = (const float*)d_in[5];
  const float* img_b   = (const float*)d_in[6];
  const float* img_g   = (const float*)d_in[7];
  const float* img_be  = (const float*)d_in[8];
  const float* img_m   = (const float*)d_in[9];
  const float* img_v   = (const float*)d_in[10];
  const float* g1_Wih  = (const float*)d_in[11];
  const float* g1_Whh  = (const float*)d_in[12];
  const float* g1_bih  = (const float*)d_in[13];
  const float* g1_bhh  = (const float*)d_in[14];
  const float* tl_W    = (const float*)d_in[15];
  const float* tl_b    = (const float*)d_in[16];
  const float* t_g     = (const float*)d_in[17];
  const float* t_be    = (const float*)d_in[18];
  const float* t_m     = (const float*)d_in[19];
  const float* t_v     = (const float*)d_in[20];
  const float* g2_Wih  = (const float*)d_in[21];
  const float* g2_Whh  = (const float*)d_in[22];
  const float* g2_bih  = (const float*)d_in[23];
  const float* g2_bhh  = (const float*)d_in[24];
  const float* cl_W    = (const float*)d_in[25];
  const float* cl_b    = (const float*)d_in[26];
  const float* c_g     = (const float*)d_in[27];
  const float* c_be    = (const float*)d_in[28];
  const float* c_m     = (const float*)d_in[29];
  const float* c_v     = (const float*)d_in[30];
  const float* a_Win   = (const float*)d_in[31];
  const float* a_bin   = (const float*)d_in[32];
  const float* a_Wout  = (const float*)d_in[33];
  const float* a_bout  = (const float*)d_in[34];
  const float* pred_W  = (const float*)d_in[35];
  const float* pred_b  = (const float*)d_in[36];

  char* ws = (char*)d_ws;
  size_t o = 0;
  auto alloc = [&](size_t sz){ size_t r = o; o += (sz + 255) & ~(size_t)255; return r; };

  // bf16 weight copies
  size_t o_g1Wih = alloc(384ull*2048*2);
  size_t o_tlW   = alloc(256ull*128*2);
  size_t o_g2Wih = alloc(768ull*256*2);
  size_t o_g2Whh = alloc(768ull*256*2);      // f16 copy for gru2
  size_t o_clW   = alloc(256ull*256*2);
  size_t o_aWin  = alloc(768ull*256*2);
  size_t o_aWout = alloc(256ull*256*2);
  size_t o_imgW  = alloc(256ull*2048*2);
  size_t o_predW = alloc(192ull*256*2);
  size_t o_predb = alloc(192ull*4);
  size_t o_imgfea= alloc(128ull*256*2);      // bf16
  size_t o_mean  = alloc(128ull*256*4);
  size_t o_len   = alloc(128ull*4);
  size_t o_R0    = alloc(33554432ull);        // xp2(f16)@+0, hs2(bf16)@+25165824 ; later osum@+0, last@+8388608
  size_t o_RB    = alloc(25165824ull);        // xp1(f16)@+0, hs1@+12582912 ; later qkv2@+0
  size_t o_tfea  = alloc(16384ull*256*2);     // text_fea bf16
  size_t o_qkv1  = alloc(16384ull*768*2);     // later logits (f32 [16384][192]) @ +0
  size_t o_cfea  = alloc(16384ull*256*2);
  size_t o_qkv0  = alloc(128ull*768*2);
  size_t o_loss  = alloc(16384ull*4);
  (void)ws_size; (void)in_sizes; (void)n_in; (void)out_size;

  unsigned short* g1Wih_bf = (unsigned short*)(ws + o_g1Wih);
  unsigned short* tlW_bf   = (unsigned short*)(ws + o_tlW);
  unsigned short* g2Wih_bf = (unsigned short*)(ws + o_g2Wih);
  f16*            g2Whh_f  = (f16*)(ws + o_g2Whh);
  unsigned short* clW_bf   = (unsigned short*)(ws + o_clW);
  unsigned short* aWin_bf  = (unsigned short*)(ws + o_aWin);
  unsigned short* aWout_bf = (unsigned short*)(ws + o_aWout);
  unsigned short* imgW_bf  = (unsigned short*)(ws + o_imgW);
  unsigned short* predW_bf = (unsigned short*)(ws + o_predW);
  float*          predb_p  = (float*)(ws + o_predb);
  unsigned short* img_fea  = (unsigned short*)(ws + o_imgfea);
  float*          meanb    = (float*)(ws + o_mean);
  float*          len_info = (float*)(ws + o_len);
  f16*            xp2      = (f16*)(ws + o_R0);
  unsigned short* hs2      = (unsigned short*)(ws + o_R0 + 25165824ull);
  unsigned short* osum     = (unsigned short*)(ws + o_R0);
  unsigned short* lastb    = (unsigned short*)(ws + o_R0 + 8388608ull);
  f16*            xp1      = (f16*)(ws + o_RB);
  unsigned short* hs1      = (unsigned short*)(ws + o_RB + 12582912ull);
  unsigned short* qkv2     = (unsigned short*)(ws + o_RB);
  unsigned short* tfea     = (unsigned short*)(ws + o_tfea);
  unsigned short* qkv1     = (unsigned short*)(ws + o_qkv1);
  float*          logits   = (float*)(ws + o_qkv1);
  unsigned short* cfea     = (unsigned short*)(ws + o_cfea);
  unsigned short* qkv0     = (unsigned short*)(ws + o_qkv0);
  float*          loss_raw = (float*)(ws + o_loss);
  float*          outp     = (float*)d_out;

  // one fused weight-conversion launch (8 segments)
  conv_all_k<<<2016, 256, 0, stream>>>(
      g1_Wih, tl_W, g2_Wih, g2_Whh, cl_W, a_Win, a_Wout, img_W,
      g1Wih_bf, tlW_bf, g2Wih_bf, g2Whh_f, clW_bf, aWin_bf, aWout_bf, imgW_bf);
  pred_pad_k<<<192, 256, 0, stream>>>(pred_W, pred_b, predW_bf, predb_p);

  // img encoder: Linear + BN + ReLU  -> img_fea (bf16)
  gemm128_k<2, true, 1><<<dim3(2, 1), 256, 0, stream>>>(
      img_emb, imgW_bf, img_b, img_g, img_be, img_m, img_v, img_fea, 128, 256, 2048);

  // xp1 = text_embs @ g1_Wih^T + bih  -> f16
  gemm128_k<1, false, 1><<<dim3(3, 128), 256, 0, stream>>>(
      text_embs, g1Wih_bf, g1_bih, nullptr, nullptr, nullptr, nullptr, xp1, 16384, 384, 2048);

  // GRU1 scan -> relu(h) bf16  (512 threads, round-15 config)
  gru1_scan_k<<<128, 512, 0, stream>>>(g1_Whh, g1_bhh, xp1, hs1);

  // tl: Linear + BN + ReLU -> text_fea
  gemm128_k<2, true, 0><<<dim3(2, 128), 256, 0, stream>>>(
      hs1, tlW_bf, tl_b, t_g, t_be, t_m, t_v, tfea, 16384, 256, 128);

  // mean over timesteps (contrast folded into xp2 staging)
  mean_k<<<128, 256, 0, stream>>>(tfea, len_mask, meanb, len_info);

  // xp2 = (tfea - mean) @ g2_Wih^T + bih   (A_MODE=2: subtract mean during staging)
  gemm128_k<1, false, 2><<<dim3(6, 128), 256, 0, stream>>>(
      tfea, g2Wih_bf, g2_bih, nullptr, nullptr, meanb, nullptr, xp2, 16384, 768, 256);

  // GRU2 scan (r in regs; z,n streamed from L2; h only in LDS)
  gru2_scan_k<<<128, 512, 0, stream>>>(g2Whh_f, g2_bhh, xp2, hs2);

  // cl: Linear + BN + ReLU -> contrast_fea
  gemm128_k<2, true, 0><<<dim3(2, 128), 256, 0, stream>>>(
      hs2, clW_bf, cl_b, c_g, c_be, c_m, c_v, cfea, 16384, 256, 256);

  // qkv projections for the 3 tokens
  gemm128_k<2, false, 0><<<dim3(6, 1), 256, 0, stream>>>(
      img_fea, aWin_bf, a_bin, nullptr, nullptr, nullptr, nullptr, qkv0, 128, 768, 256);
  gemm128_k<2, false, 0><<<dim3(6, 128), 256, 0, stream>>>(
      tfea, aWin_bf, a_bin, nullptr, nullptr, nullptr, nullptr, qkv1, 16384, 768, 256);
  gemm128_k<2, false, 0><<<dim3(6, 128), 256, 0, stream>>>(
      cfea, aWin_bf, a_bin, nullptr, nullptr, nullptr, nullptr, qkv2, 16384, 768, 256);

  // fused 3x3 attention -> mean over tokens (pre-projection)
  attn_k<<<128, 256, 0, stream>>>(qkv0, qkv1, qkv2, osum);

  // output projection (applied to token-mean; linearity) -> last
  gemm128_k<2, false, 0><<<dim3(2, 128), 256, 0, stream>>>(
      osum, aWout_bf, a_bout, nullptr, nullptr, nullptr, nullptr, lastb, 16384, 256, 256);

  // logits (N padded to 192) — 64-tile kernel
  gemm_k<0, false, false><<<dim3(3, 256), 256, 0, stream>>>(
      lastb, predW_bf, predb_p, nullptr, nullptr, nullptr, nullptr, logits, 16384, 192, 256);

  // per-row CE loss, then masked mean
  loss_k<<<16384, 64, 0, stream>>>(logits, label_mask, labels, loss_raw);
  final_k<<<1, 256, 0, stream>>>(loss_raw, len_mask, len_info, outp);
}

// Round 18
// 596.142 us; speedup vs baseline: 1.0828x; 1.0020x over previous
//
#include <hip/hip_runtime.h>

// ---------------- types & helpers ----------------
typedef __attribute__((ext_vector_type(8))) short short8;   // 8 bf16 (4 VGPR)
typedef __attribute__((ext_vector_type(4))) float f32x4;
typedef _Float16 f16;
typedef __attribute__((ext_vector_type(2))) _Float16 f16x2;
typedef __attribute__((ext_vector_type(8))) _Float16 f16x8;

__device__ inline float bf2f(unsigned short u){
  union{float f; unsigned u32;} x; x.u32 = ((unsigned)u) << 16; return x.f;
}
__device__ inline unsigned short f2bf(float f){
  union{float f; unsigned u;} x; x.f = f;
  unsigned r = (x.u + 0x7FFFu + ((x.u >> 16) & 1u)) >> 16;
  return (unsigned short)r;
}

#if defined(__has_builtin)
#  if __has_builtin(__builtin_amdgcn_fdot2)
#    define HAS_FDOT2 1
#  endif
#endif
__device__ inline float dot2f(f16x2 a, f16x2 b, float c){
#ifdef HAS_FDOT2
  return __builtin_amdgcn_fdot2(a, b, c, false);
#else
  return c + (float)a.x * (float)b.x + (float)a.y * (float)b.y;
#endif
}
__device__ inline f16x2 asf16x2(int v){ return __builtin_bit_cast(f16x2, v); }
__device__ inline int pack2(float lo, float hi){
  f16x2 p = f16x2{(f16)lo, (f16)hi};
  return __builtin_bit_cast(int, p);
}

__device__ inline float sigmoidf_(float x){ return 1.f / (1.f + __expf(-x)); }
__device__ inline float tanh_fast(float x){ float e = __expf(2.f * x); return 1.f - 2.f / (e + 1.f); }

// DPP quad-permute butterfly adds (VALU pipe)
__device__ inline float dpp_xor1(float x){
  return __int_as_float(__builtin_amdgcn_update_dpp(0, __float_as_int(x), 0xB1, 0xF, 0xF, true));
}
__device__ inline float dpp_xor2(float x){
  return __int_as_float(__builtin_amdgcn_update_dpp(0, __float_as_int(x), 0x4E, 0xF, 0xF, true));
}

__device__ inline void load8bf(const unsigned short* p, float* o){
  uint4 q = *(const uint4*)p;
  o[0]=bf2f((unsigned short)(q.x & 0xffffu)); o[1]=bf2f((unsigned short)(q.x >> 16));
  o[2]=bf2f((unsigned short)(q.y & 0xffffu)); o[3]=bf2f((unsigned short)(q.y >> 16));
  o[4]=bf2f((unsigned short)(q.z & 0xffffu)); o[5]=bf2f((unsigned short)(q.z >> 16));
  o[6]=bf2f((unsigned short)(q.w & 0xffffu)); o[7]=bf2f((unsigned short)(q.w >> 16));
}

// async global->LDS, 16 bytes per lane (lds dest = wave-uniform base + lane*16)
#define GLL16(g, l) __builtin_amdgcn_global_load_lds(                      \
    (const __attribute__((address_space(1))) void*)(g),                    \
    (__attribute__((address_space(3))) void*)(l), 16, 0, 0)

// ---------------- fused weight conversion (8 segments, one launch) ----------------
__global__ __launch_bounds__(256) void conv_all_k(
    const float* __restrict__ s0, const float* __restrict__ s1,
    const float* __restrict__ s2, const float* __restrict__ s3,
    const float* __restrict__ s4, const float* __restrict__ s5,
    const float* __restrict__ s6, const float* __restrict__ s7,
    unsigned short* __restrict__ d0, unsigned short* __restrict__ d1,
    unsigned short* __restrict__ d2, f16* __restrict__ d3,
    unsigned short* __restrict__ d4, unsigned short* __restrict__ d5,
    unsigned short* __restrict__ d6, unsigned short* __restrict__ d7)
{
  int i = blockIdx.x * 256 + threadIdx.x;
  if (i >= 516096) return;
  const float* src; int local; int mode = 0; unsigned short* dst = nullptr; f16* dstf = nullptr;
  if (i < 196608)      { src = s0; local = i;           dst = d0; }
  else if (i < 204800) { src = s1; local = i - 196608;  dst = d1; }
  else if (i < 253952) { src = s2; local = i - 204800;  dst = d2; }
  else if (i < 303104) { src = s3; local = i - 253952;  dstf = d3; mode = 1; }
  else if (i < 319488) { src = s4; local = i - 303104;  dst = d4; }
  else if (i < 368640) { src = s5; local = i - 319488;  dst = d5; }
  else if (i < 385024) { src = s6; local = i - 368640;  dst = d6; }
  else                 { src = s7; local = i - 385024;  dst = d7; }
  float4 v = ((const float4*)src)[local];
  if (mode == 0) {
    union { unsigned short s[4]; uint2 q; } u;
    u.s[0]=f2bf(v.x); u.s[1]=f2bf(v.y); u.s[2]=f2bf(v.z); u.s[3]=f2bf(v.w);
    ((uint2*)dst)[local] = u.q;
  } else {
    union { f16 s[4]; uint2 q; } u;
    u.s[0]=(f16)v.x; u.s[1]=(f16)v.y; u.s[2]=(f16)v.z; u.s[3]=(f16)v.w;
    ((uint2*)dstf)[local] = u.q;
  }
}

// pred_W [190][256] -> [192][256] zero-padded bf16; pred_b -> [192] zero-padded f32
__global__ __launch_bounds__(256) void pred_pad_k(const float* __restrict__ W,
                                                  const float* __restrict__ b,
                                                  unsigned short* __restrict__ Wd,
                                                  float* __restrict__ bd){
  int i = blockIdx.x * 256 + threadIdx.x;   // 192*256 threads
  int j = i >> 8;
  Wd[i] = (j < 190) ? f2bf(W[i]) : (unsigned short)0;
  if (i < 192) bd[i] = (i < 190) ? b[i] : 0.f;
}

// ---------------- 128x128-tile MFMA GEMM (m97 structure) ----------------
// A_MODE: 0 = bf16 via global_load_lds; 1 = f32 reg-convert; 2 = bf16 minus mean.
template<int OUT_T, bool BN, int A_MODE>
__global__ __launch_bounds__(256) void gemm128_k(
    const void* __restrict__ Ap, const unsigned short* __restrict__ Bw,
    const float* __restrict__ bias,
    const float* __restrict__ gam, const float* __restrict__ bet,
    const float* __restrict__ mu,  const float* __restrict__ var,
    void* __restrict__ Cp, int M, int N, int K)
{
  __shared__ __align__(16) unsigned short As[4096];   // [128][32]
  __shared__ __align__(16) unsigned short Bs[4096];
  const int tid  = threadIdx.x;
  const int lane = tid & 63, wid = tid >> 6;
  const int wm = wid & 1, wn = wid >> 1;
  const int bm = blockIdx.y << 7, bn = blockIdx.x << 7;
  const int rA = tid >> 2, seg = tid & 3;

  f32x4 acc[4][4];
  #pragma unroll
  for (int i = 0; i < 4; i++)
    #pragma unroll
    for (int j = 0; j < 4; j++)
      acc[i][j] = f32x4{0.f, 0.f, 0.f, 0.f};

  const unsigned short* Abf = (const unsigned short*)Ap;
  const float* Af = (const float*)Ap;
  char* asb = (char*)As;
  char* bsb = (char*)Bs;
  char* asw = asb + wid * 1024;
  char* bsw = bsb + wid * 1024;

  for (int k0 = 0; k0 < K; k0 += 32) {
    if (A_MODE == 1) {
      #pragma unroll
      for (int beta = 0; beta < 2; beta++) {
        const float* src = Af + (size_t)(bm + rA + beta * 64) * K + k0 + seg * 8;
        float4 v0 = *(const float4*)src;
        float4 v1 = *(const float4*)(src + 4);
        union { unsigned short s[8]; uint4 q; } u;
        u.s[0]=f2bf(v0.x); u.s[1]=f2bf(v0.y); u.s[2]=f2bf(v0.z); u.s[3]=f2bf(v0.w);
        u.s[4]=f2bf(v1.x); u.s[5]=f2bf(v1.y); u.s[6]=f2bf(v1.z); u.s[7]=f2bf(v1.w);
        *(uint4*)(asb + beta * 4096 + tid * 16) = u.q;
      }
    } else if (A_MODE == 2) {
      const float* mrow = mu + (size_t)(bm >> 7) * 256 + k0 + seg * 8;
      float4 m0 = *(const float4*)mrow;
      float4 m1 = *(const float4*)(mrow + 4);
      #pragma unroll
      for (int beta = 0; beta < 2; beta++) {
        const unsigned short* src = Abf + (size_t)(bm + rA + beta * 64) * K + k0 + seg * 8;
        float av[8];
        load8bf(src, av);
        union { unsigned short s[8]; uint4 q; } u;
        u.s[0]=f2bf(av[0]-m0.x); u.s[1]=f2bf(av[1]-m0.y); u.s[2]=f2bf(av[2]-m0.z); u.s[3]=f2bf(av[3]-m0.w);
        u.s[4]=f2bf(av[4]-m1.x); u.s[5]=f2bf(av[5]-m1.y); u.s[6]=f2bf(av[6]-m1.z); u.s[7]=f2bf(av[7]-m1.w);
        *(uint4*)(asb + beta * 4096 + tid * 16) = u.q;
      }
    } else {
      GLL16(Abf + (size_t)(bm + rA)      * K + k0 + seg * 8, asw);
      GLL16(Abf + (size_t)(bm + rA + 64) * K + k0 + seg * 8, asw + 4096);
    }
    GLL16(Bw + (size_t)(bn + rA)      * K + k0 + seg * 8, bsw);
    GLL16(Bw + (size_t)(bn + rA + 64) * K + k0 + seg * 8, bsw + 4096);
    __syncthreads();

    short8 a[4], b[4];
    #pragma unroll
    for (int f = 0; f < 4; f++) {
      int ra = wm * 64 + f * 16 + (lane & 15);
      a[f] = *(const short8*)(asb + ra * 64 + (lane >> 4) * 16);
      int rb = wn * 64 + f * 16 + (lane & 15);
      b[f] = *(const short8*)(bsb + rb * 64 + (lane >> 4) * 16);
    }
    #pragma unroll
    for (int fm = 0; fm < 4; fm++)
      #pragma unroll
      for (int fn = 0; fn < 4; fn++)
        acc[fm][fn] = __builtin_amdgcn_mfma_f32_16x16x32_bf16(a[fm], b[fn], acc[fm][fn], 0, 0, 0);
    __syncthreads();
  }

  #pragma unroll
  for (int fn = 0; fn < 4; fn++) {
    int col = bn + wn * 64 + fn * 16 + (lane & 15);
    float bs = bias[col];
    float sc = 1.f, sh = 0.f;
    if (BN) { float s = gam[col] * rsqrtf(var[col] + 1e-5f); sc = s; sh = bet[col] - mu[col] * s; }
    #pragma unroll
    for (int fm = 0; fm < 4; fm++) {
      int row = bm + wm * 64 + fm * 16 + ((lane >> 4) << 2);
      #pragma unroll
      for (int j = 0; j < 4; j++) {
        float v = acc[fm][fn][j] + bs;
        if (BN) { v = v * sc + sh; v = fmaxf(v, 0.f); }
        size_t idx = (size_t)(row + j) * N + col;
        if (OUT_T == 1) ((f16*)Cp)[idx] = (f16)v;
        else            ((unsigned short*)Cp)[idx] = f2bf(v);
      }
    }
  }
}

// ---------------- fused QKV GEMM: 3 sources x same B (aWin), N=768, K=256 ----------------
// blockIdx.y: [0,128) -> tfea->qkv1; [128,256) -> cfea->qkv2; 256 -> img_fea->qkv0.
__global__ __launch_bounds__(256) void gemmqkv_k(
    const unsigned short* __restrict__ tfea, const unsigned short* __restrict__ cfea,
    const unsigned short* __restrict__ imgf, const unsigned short* __restrict__ Bw,
    const float* __restrict__ bias,
    unsigned short* __restrict__ q1, unsigned short* __restrict__ q2,
    unsigned short* __restrict__ q0)
{
  const int N = 768, K = 256;
  __shared__ __align__(16) unsigned short As[4096];
  __shared__ __align__(16) unsigned short Bs[4096];
  const int tid  = threadIdx.x;
  const int lane = tid & 63, wid = tid >> 6;
  const int wm = wid & 1, wn = wid >> 1;
  const int y = blockIdx.y;
  const unsigned short* Abf; unsigned short* Cp; int bm;
  if (y < 128)      { Abf = tfea; Cp = q1; bm = y << 7; }
  else if (y < 256) { Abf = cfea; Cp = q2; bm = (y - 128) << 7; }
  else              { Abf = imgf; Cp = q0; bm = 0; }
  const int bn = blockIdx.x << 7;
  const int rA = tid >> 2, seg = tid & 3;

  f32x4 acc[4][4];
  #pragma unroll
  for (int i = 0; i < 4; i++)
    #pragma unroll
    for (int j = 0; j < 4; j++)
      acc[i][j] = f32x4{0.f, 0.f, 0.f, 0.f};

  char* asb = (char*)As;
  char* bsb = (char*)Bs;
  char* asw = asb + wid * 1024;
  char* bsw = bsb + wid * 1024;

  for (int k0 = 0; k0 < K; k0 += 32) {
    GLL16(Abf + (size_t)(bm + rA)      * K + k0 + seg * 8, asw);
    GLL16(Abf + (size_t)(bm + rA + 64) * K + k0 + seg * 8, asw + 4096);
    GLL16(Bw + (size_t)(bn + rA)      * K + k0 + seg * 8, bsw);
    GLL16(Bw + (size_t)(bn + rA + 64) * K + k0 + seg * 8, bsw + 4096);
    __syncthreads();

    short8 a[4], b[4];
    #pragma unroll
    for (int f = 0; f < 4; f++) {
      int ra = wm * 64 + f * 16 + (lane & 15);
      a[f] = *(const short8*)(asb + ra * 64 + (lane >> 4) * 16);
      int rb = wn * 64 + f * 16 + (lane & 15);
      b[f] = *(const short8*)(bsb + rb * 64 + (lane >> 4) * 16);
    }
    #pragma unroll
    for (int fm = 0; fm < 4; fm++)
      #pragma unroll
      for (int fn = 0; fn < 4; fn++)
        acc[fm][fn] = __builtin_amdgcn_mfma_f32_16x16x32_bf16(a[fm], b[fn], acc[fm][fn], 0, 0, 0);
    __syncthreads();
  }

  #pragma unroll
  for (int fn = 0; fn < 4; fn++) {
    int col = bn + wn * 64 + fn * 16 + (lane & 15);
    float bs = bias[col];
    #pragma unroll
    for (int fm = 0; fm < 4; fm++) {
      int row = bm + wm * 64 + fm * 16 + ((lane >> 4) << 2);
      #pragma unroll
      for (int j = 0; j < 4; j++) {
        float v = acc[fm][fn][j] + bs;
        Cp[(size_t)(row + j) * N + col] = f2bf(v);
      }
    }
  }
}

// ---------------- 64-tile MFMA GEMM (kept for logits, N=192) ----------------
template<int OUT_T, bool BN, bool AF32>
__global__ __launch_bounds__(256) void gemm_k(
    const void* __restrict__ Ap, const unsigned short* __restrict__ Bw,
    const float* __restrict__ bias,
    const float* __restrict__ gam, const float* __restrict__ bet,
    const float* __restrict__ mu,  const float* __restrict__ var,
    void* __restrict__ Cp, int M, int N, int K)
{
  __shared__ unsigned short As[64][40];
  __shared__ unsigned short Bs[64][40];
  const int tid  = threadIdx.x;
  const int lane = tid & 63, wid = tid >> 6;
  const int wm = wid & 1, wn = wid >> 1;
  const int bm = blockIdx.y << 6, bn = blockIdx.x << 6;
  const int srow = tid >> 2, sseg = tid & 3;

  f32x4 acc[2][2];
  #pragma unroll
  for (int i = 0; i < 2; i++)
    #pragma unroll
    for (int j = 0; j < 2; j++)
      acc[i][j] = f32x4{0.f, 0.f, 0.f, 0.f};

  const unsigned short* Abf = (const unsigned short*)Ap;
  const float* Af = (const float*)Ap;

  for (int k0 = 0; k0 < K; k0 += 32) {
    if (AF32) {
      const float* src = Af + (size_t)(bm + srow) * K + k0 + sseg * 8;
      float4 v0 = *(const float4*)(src);
      float4 v1 = *(const float4*)(src + 4);
      union { unsigned short s[8]; uint4 q; } u;
      u.s[0]=f2bf(v0.x); u.s[1]=f2bf(v0.y); u.s[2]=f2bf(v0.z); u.s[3]=f2bf(v0.w);
      u.s[4]=f2bf(v1.x); u.s[5]=f2bf(v1.y); u.s[6]=f2bf(v1.z); u.s[7]=f2bf(v1.w);
      *(uint4*)&As[srow][sseg * 8] = u.q;
    } else {
      *(uint4*)&As[srow][sseg * 8] =
          *(const uint4*)(Abf + (size_t)(bm + srow) * K + k0 + sseg * 8);
    }
    *(uint4*)&Bs[srow][sseg * 8] =
        *(const uint4*)(Bw + (size_t)(bn + srow) * K + k0 + sseg * 8);
    __syncthreads();

    short8 a0 = *(const short8*)&As[wm * 32 +      (lane & 15)][(lane >> 4) * 8];
    short8 a1 = *(const short8*)&As[wm * 32 + 16 + (lane & 15)][(lane >> 4) * 8];
    short8 b0 = *(const short8*)&Bs[wn * 32 +      (lane & 15)][(lane >> 4) * 8];
    short8 b1 = *(const short8*)&Bs[wn * 32 + 16 + (lane & 15)][(lane >> 4) * 8];
    acc[0][0] = __builtin_amdgcn_mfma_f32_16x16x32_bf16(a0, b0, acc[0][0], 0, 0, 0);
    acc[0][1] = __builtin_amdgcn_mfma_f32_16x16x32_bf16(a0, b1, acc[0][1], 0, 0, 0);
    acc[1][0] = __builtin_amdgcn_mfma_f32_16x16x32_bf16(a1, b0, acc[1][0], 0, 0, 0);
    acc[1][1] = __builtin_amdgcn_mfma_f32_16x16x32_bf16(a1, b1, acc[1][1], 0, 0, 0);
    __syncthreads();
  }

  #pragma unroll
  for (int fn = 0; fn < 2; fn++) {
    int col = bn + wn * 32 + fn * 16 + (lane & 15);
    float bs = bias[col];
    float sc = 1.f, sh = 0.f;
    if (BN) { float s = gam[col] * rsqrtf(var[col] + 1e-5f); sc = s; sh = bet[col] - mu[col] * s; }
    #pragma unroll
    for (int fm = 0; fm < 2; fm++) {
      int row = bm + wm * 32 + fm * 16 + ((lane >> 4) << 2);
      #pragma unroll
      for (int j = 0; j < 4; j++) {
        float v = acc[fm][fn][j] + bs;
        if (BN) { v = v * sc + sh; v = fmaxf(v, 0.f); }
        size_t idx = (size_t)(row + j) * N + col;
        if (OUT_T == 0)      ((float*)Cp)[idx] = v;
        else if (OUT_T == 1) ((f16*)Cp)[idx]   = (f16)v;
        else                 ((unsigned short*)Cp)[idx] = f2bf(v);
      }
    }
  }
}

// ---------------- GRU scans ----------------
// GRU2 (r,z in opaque regs; n streamed from L2; h-only LDS): 512 thr, jj=tid>>1, kh=tid&1.
__global__ __launch_bounds__(512, 2) void gru2_scan_k(
    const f16* __restrict__ Wf,              // [768][256] f16
    const float* __restrict__ bhh,
    const f16* __restrict__ xp, unsigned short* __restrict__ hs_relu)
{
  const int b = blockIdx.x;
  const int tid = threadIdx.x;
  const int jj = tid >> 1, kh = tid & 1;
  __shared__ __align__(16) f16 hbuf[2][256];

  int wri[64], wzi[64];
  #pragma unroll
  for (int i = 0; i < 16; i++) {
    const int kb = kh * 128 + i * 8;
    uint4 q;
    q = *(const uint4*)&Wf[(size_t)(jj      ) * 256 + kb];
    wri[4*i+0] = (int)q.x; wri[4*i+1] = (int)q.y; wri[4*i+2] = (int)q.z; wri[4*i+3] = (int)q.w;
    q = *(const uint4*)&Wf[(size_t)(jj + 256) * 256 + kb];
    wzi[4*i+0] = (int)q.x; wzi[4*i+1] = (int)q.y; wzi[4*i+2] = (int)q.z; wzi[4*i+3] = (int)q.w;
  }
  #pragma unroll
  for (int i = 0; i < 64; i++)
    asm volatile("" : "+v"(wri[i]), "+v"(wzi[i]));

  const f16* nsrc = Wf + (size_t)(512 + jj) * 256 + kh * 128;

  const float br = bhh[jj], bz = bhh[jj + 256], bn2 = bhh[jj + 512];
  if (tid < 256) hbuf[0][tid] = (f16)0.f;
  float hprev = 0.f;
  f16 pxr = (f16)0.f, pxz = (f16)0.f, pxn = (f16)0.f;
  if (kh == 0) {
    const f16* x0 = xp + (size_t)(b * 128) * 768;
    pxr = x0[jj]; pxz = x0[256 + jj]; pxn = x0[512 + jj];
  }
  __syncthreads();
  int cur = 0;
  for (int t = 0; t < 128; t++) {
    float xr = (float)pxr, xz = (float)pxz, xn = (float)pxn;
    if (kh == 0) {
      const int tn = (t < 127) ? (t + 1) : 127;
      const f16* xnr = xp + (size_t)(b * 128 + tn) * 768;
      pxr = xnr[jj]; pxz = xnr[256 + jj]; pxn = xnr[512 + jj];
    }
    uint4 nb[4];
    #pragma unroll
    for (int c = 0; c < 4; c++) nb[c] = *(const uint4*)(nsrc + c * 8);

    const char* hb = (const char*)hbuf[cur] + kh * 256;
    float ar = 0.f, az = 0.f, an = 0.f;
    #pragma unroll
    for (int i = 0; i < 16; i++) {
      f16x8 hv = *(const f16x8*)(hb + i * 16);
      f16x8 nv = __builtin_bit_cast(f16x8, nb[i & 3]);
      if (i < 12) nb[i & 3] = *(const uint4*)(nsrc + (i + 4) * 8);
      #pragma unroll
      for (int u = 0; u < 4; u++) {
        f16x2 hp = f16x2{hv[2*u], hv[2*u+1]};
        ar = dot2f(asf16x2(wri[4*i+u]), hp, ar);
        az = dot2f(asf16x2(wzi[4*i+u]), hp, az);
        an = dot2f(f16x2{nv[2*u], nv[2*u+1]}, hp, an);
      }
    }
    ar += dpp_xor1(ar);
    az += dpp_xor1(az);
    an += dpp_xor1(an);
    if (kh == 0) {
      float r = sigmoidf_(xr + ar + br);
      float z = sigmoidf_(xz + az + bz);
      float n = tanh_fast(xn + r * (an + bn2));
      float hnew = (1.f - z) * n + z * hprev;
      hprev = hnew;
      hbuf[cur ^ 1][jj] = (f16)hnew;
      hs_relu[(size_t)(b * 128 + t) * 256 + jj] = f2bf(fmaxf(hnew, 0.f));
    }
    __syncthreads();
    cur ^= 1;
  }
}

// GRU1 (round-15 best): H=128, gates 384. 512 thr: jj = tid>>2, kh = tid&3.
__global__ __launch_bounds__(512, 4) void gru1_scan_k(
    const float* __restrict__ Whh, const float* __restrict__ bhh,
    const f16* __restrict__ xp, unsigned short* __restrict__ hs_relu)
{
  const int b = blockIdx.x;
  const int tid = threadIdx.x;
  const int jj = tid >> 2, kh = tid & 3;
  __shared__ __align__(16) f16 hbuf[2][128];

  int wri[16], wzi[16], wni[16];
  #pragma unroll
  for (int i = 0; i < 4; i++) {
    const int kb = kh * 32 + i * 8;
    float4 f0, f1;
    f0 = *(const float4*)&Whh[(size_t)(jj      ) * 128 + kb];
    f1 = *(const float4*)&Whh[(size_t)(jj      ) * 128 + kb + 4];
    wri[4*i+0] = pack2(f0.x, f0.y); wri[4*i+1] = pack2(f0.z, f0.w);
    wri[4*i+2] = pack2(f1.x, f1.y); wri[4*i+3] = pack2(f1.z, f1.w);
    f0 = *(const float4*)&Whh[(size_t)(jj + 128) * 128 + kb];
    f1 = *(const float4*)&Whh[(size_t)(jj + 128) * 128 + kb + 4];
    wzi[4*i+0] = pack2(f0.x, f0.y); wzi[4*i+1] = pack2(f0.z, f0.w);
    wzi[4*i+2] = pack2(f1.x, f1.y); wzi[4*i+3] = pack2(f1.z, f1.w);
    f0 = *(const float4*)&Whh[(size_t)(jj + 256) * 128 + kb];
    f1 = *(const float4*)&Whh[(size_t)(jj + 256) * 128 + kb + 4];
    wni[4*i+0] = pack2(f0.x, f0.y); wni[4*i+1] = pack2(f0.z, f0.w);
    wni[4*i+2] = pack2(f1.x, f1.y); wni[4*i+3] = pack2(f1.z, f1.w);
  }
  #pragma unroll
  for (int i = 0; i < 16; i++)
    asm volatile("" : "+v"(wri[i]), "+v"(wzi[i]), "+v"(wni[i]));

  const float br = bhh[jj], bz = bhh[jj + 128], bn2 = bhh[jj + 256];
  if (tid < 128) hbuf[0][tid] = (f16)0.f;
  float hprev = 0.f;
  f16 pxr = (f16)0.f, pxz = (f16)0.f, pxn = (f16)0.f;
  if (kh == 0) {
    const f16* x0 = xp + (size_t)(b * 128) * 384;
    pxr = x0[jj]; pxz = x0[128 + jj]; pxn = x0[256 + jj];
  }
  __syncthreads();
  int cur = 0;
  for (int t = 0; t < 128; t++) {
    float xr = (float)pxr, xz = (float)pxz, xn = (float)pxn;
    if (kh == 0) {
      const int tn = (t < 127) ? (t + 1) : 127;
      const f16* xnr = xp + (size_t)(b * 128 + tn) * 384;
      pxr = xnr[jj]; pxz = xnr[128 + jj]; pxn = xnr[256 + jj];
    }
    const char* hb = (const char*)hbuf[cur] + kh * 64;
    float ar = 0.f, az = 0.f, an = 0.f;
    #pragma unroll
    for (int c = 0; c < 4; c++) {
      f16x8 hv = *(const f16x8*)(hb + c * 16);
      #pragma unroll
      for (int u = 0; u < 4; u++) {
        f16x2 hp = f16x2{hv[2*u], hv[2*u+1]};
        ar = dot2f(asf16x2(wri[4*c+u]), hp, ar);
        az = dot2f(asf16x2(wzi[4*c+u]), hp, az);
        an = dot2f(asf16x2(wni[4*c+u]), hp, an);
      }
    }
    ar += dpp_xor1(ar); ar += dpp_xor2(ar);
    az += dpp_xor1(az); az += dpp_xor2(az);
    an += dpp_xor1(an); an += dpp_xor2(an);
    if (kh == 0) {
      float r = sigmoidf_(xr + ar + br);
      float z = sigmoidf_(xz + az + bz);
      float n = tanh_fast(xn + r * (an + bn2));
      float hnew = (1.f - z) * n + z * hprev;
      hprev = hnew;
      hbuf[cur ^ 1][jj] = (f16)hnew;
      hs_relu[(size_t)(b * 128 + t) * 128 + jj] = f2bf(fmaxf(hnew, 0.f));
    }
    __syncthreads();
    cur ^= 1;
  }
}

// ---------------- mean over timesteps ----------------
__global__ __launch_bounds__(256) void mean_k(const unsigned short* __restrict__ tf,
                                              const float* __restrict__ len_mask,
                                              float* __restrict__ mean,
                                              float* __restrict__ len_info){
  int b = blockIdx.x, c = threadIdx.x;
  float acc = 0.f;
  for (int s = 0; s < 128; s++) acc += bf2f(tf[(size_t)(b * 128 + s) * 256 + c]);
  float len = 0.f;
  for (int s = 0; s < 128; s++) len += len_mask[b * 128 + s];
  mean[b * 256 + c] = acc / len;
  if (c == 0) len_info[b] = len;
}

// ---------------- fused 3-token attention (thread per (n, head)) ----------------
__global__ __launch_bounds__(256) void attn_k(const unsigned short* __restrict__ qkv0,
                                              const unsigned short* __restrict__ qkv1,
                                              const unsigned short* __restrict__ qkv2,
                                              unsigned short* __restrict__ osum){
  int i = blockIdx.x * 256 + threadIdx.x;   // 32768
  int h = i & 1; int n = i >> 1; int b = n >> 7;
  const unsigned short* t0 = qkv0 + (size_t)b * 768 + h * 128;
  const unsigned short* t1 = qkv1 + (size_t)n * 768 + h * 128;
  const unsigned short* t2 = qkv2 + (size_t)n * 768 + h * 128;
  float sc[3][3];
  #pragma unroll
  for (int a = 0; a < 3; a++)
    #pragma unroll
    for (int s = 0; s < 3; s++) sc[a][s] = 0.f;
  #pragma unroll 1
  for (int dc = 0; dc < 16; dc++) {
    float q[3][8], k[3][8];
    load8bf(t0 + dc * 8, q[0]); load8bf(t1 + dc * 8, q[1]); load8bf(t2 + dc * 8, q[2]);
    load8bf(t0 + 256 + dc * 8, k[0]); load8bf(t1 + 256 + dc * 8, k[1]); load8bf(t2 + 256 + dc * 8, k[2]);
    #pragma unroll
    for (int a = 0; a < 3; a++)
      #pragma unroll
      for (int s = 0; s < 3; s++) {
        float d = 0.f;
        #pragma unroll
        for (int e = 0; e < 8; e++) d += q[a][e] * k[s][e];
        sc[a][s] += d;
      }
  }
  const float scale = 0.08838834764831845f;   // 1/sqrt(128)
  float w[3] = {0.f, 0.f, 0.f};
  #pragma unroll
  for (int a = 0; a < 3; a++) {
    float s0 = sc[a][0] * scale, s1 = sc[a][1] * scale, s2 = sc[a][2] * scale;
    float m = fmaxf(s0, fmaxf(s1, s2));
    float e0 = __expf(s0 - m), e1 = __expf(s1 - m), e2 = __expf(s2 - m);
    float inv = 1.f / (e0 + e1 + e2);
    w[0] += e0 * inv; w[1] += e1 * inv; w[2] += e2 * inv;
  }
  w[0] *= (1.f / 3.f); w[1] *= (1.f / 3.f); w[2] *= (1.f / 3.f);
  unsigned short* op = osum + (size_t)n * 256 + h * 128;
  #pragma unroll 1
  for (int dc = 0; dc < 16; dc++) {
    float v0[8], v1[8], v2[8];
    load8bf(t0 + 512 + dc * 8, v0); load8bf(t1 + 512 + dc * 8, v1); load8bf(t2 + 512 + dc * 8, v2);
    union { unsigned short s[8]; uint4 q; } u;
    #pragma unroll
    for (int e = 0; e < 8; e++) u.s[e] = f2bf(w[0] * v0[e] + w[1] * v1[e] + w[2] * v2[e]);
    *(uint4*)(op + dc * 8) = u.q;
  }
}

// ---------------- softmax-CE loss per row ----------------
__global__ __launch_bounds__(64) void loss_k(const float* __restrict__ logits,
                                             const float* __restrict__ label_mask,
                                             const int* __restrict__ labels,
                                             float* __restrict__ loss_raw){
  int r = blockIdx.x; int j = threadIdx.x;
  int lab = labels[r];
  float l[3]; float m = -1e30f;
  #pragma unroll
  for (int q = 0; q < 3; q++) {
    int c = j + q * 64;
    float lv = (c < 190) ? logits[(size_t)r * 192 + c] : -1e30f;
    l[q] = lv; m = fmaxf(m, lv);
  }
  #pragma unroll
  for (int off = 32; off; off >>= 1) m = fmaxf(m, __shfl_xor(m, off));
  float se = 0.f, soh = 0.f, dot = 0.f;
  #pragma unroll
  for (int q = 0; q < 3; q++) {
    int c = j + q * 64;
    if (c < 190) {
      se += expf(l[q] - m);
      float oh = fmaxf(label_mask[(size_t)r * 190 + c], (c == lab) ? 1.f : 0.f);
      soh += oh; dot += oh * l[q];
    }
  }
  #pragma unroll
  for (int off = 32; off; off >>= 1) {
    se += __shfl_xor(se, off); soh += __shfl_xor(soh, off); dot += __shfl_xor(dot, off);
  }
  if (j == 0) loss_raw[r] = (m + logf(se)) * soh - dot;
}

__global__ __launch_bounds__(256) void final_k(const float* __restrict__ loss_raw,
                                               const float* __restrict__ len_mask,
                                               const float* __restrict__ len_info,
                                               float* __restrict__ out){
  __shared__ float sh[256];
  int t = threadIdx.x;
  float acc = 0.f;
  for (int i = t; i < 16384; i += 256) acc += loss_raw[i] * len_mask[i] / len_info[i >> 7];
  sh[t] = acc; __syncthreads();
  for (int s = 128; s; s >>= 1) { if (t < s) sh[t] += sh[t + s]; __syncthreads(); }
  if (t == 0) out[0] = sh[0] / 128.f;
}

// ---------------- launch ----------------
extern "C" void kernel_launch(void* const* d_in, const int* in_sizes, int n_in,
                              void* d_out, int out_size, void* d_ws, size_t ws_size,
                              hipStream_t stream)
{
  const float* img_emb    = (const float*)d_in[0];
  const float* text_embs  = (const float*)d_in[1];
  const float* len_mask   = (const float*)d_in[2];
  const float* label_mask = (const float*)d_in[3];
  const int*   labels     = (const int*)  d_in[4];
  const float* img_W   = (const float*)d_in[5];
  const float* img_b   = (const float*)d_in[6];
  const float* img_g   = (const float*)d_in[7];
  const float* img_be  = (const float*)d_in[8];
  const float* img_m   = (const float*)d_in[9];
  const float* img_v   = (const float*)d_in[10];
  const float* g1_Wih  = (const float*)d_in[11];
  const float* g1_Whh  = (const float*)d_in[12];
  const float* g1_bih  = (const float*)d_in[13];
  const float* g1_bhh  = (const float*)d_in[14];
  const float* tl_W    = (const float*)d_in[15];
  const float* tl_b    = (const float*)d_in[16];
  const float* t_g     = (const float*)d_in[17];
  const float* t_be    = (const float*)d_in[18];
  const float* t_m     = (const float*)d_in[19];
  const float* t_v     = (const float*)d_in[20];
  const float* g2_Wih  = (const float*)d_in[21];
  const float* g2_Whh  = (const float*)d_in[22];
  const float* g2_bih  = (const float*)d_in[23];
  const float* g2_bhh  = (const float*)d_in[24];
  const float* cl_W    = (const float*)d_in[25];
  const float* cl_b    = (const float*)d_in[26];
  const float* c_g     = (const float*)d_in[27];
  const float* c_be    = (const float*)d_in[28];
  const float* c_m     = (const float*)d_in[29];
  const float* c_v     = (const float*)d_in[30];
  const float* a_Win   = (const float*)d_in[31];
  const float* a_bin   = (const float*)d_in[32];
  const float* a_Wout  = (const float*)d_in[33];
  const float* a_bout  = (const float*)d_in[34];
  const float* pred_W  = (const float*)d_in[35];
  const float* pred_b  = (const float*)d_in[36];

  char* ws = (char*)d_ws;
  size_t o = 0;
  auto alloc = [&](size_t sz){ size_t r = o; o += (sz + 255) & ~(size_t)255; return r; };

  // bf16 weight copies
  size_t o_g1Wih = alloc(384ull*2048*2);
  size_t o_tlW   = alloc(256ull*128*2);
  size_t o_g2Wih = alloc(768ull*256*2);
  size_t o_g2Whh = alloc(768ull*256*2);      // f16 copy for gru2
  size_t o_clW   = alloc(256ull*256*2);
  size_t o_aWin  = alloc(768ull*256*2);
  size_t o_aWout = alloc(256ull*256*2);
  size_t o_imgW  = alloc(256ull*2048*2);
  size_t o_predW = alloc(192ull*256*2);
  size_t o_predb = alloc(192ull*4);
  size_t o_imgfea= alloc(128ull*256*2);      // bf16
  size_t o_mean  = alloc(128ull*256*4);
  size_t o_len   = alloc(128ull*4);
  size_t o_R0    = alloc(33554432ull);        // xp2(f16)@+0, hs2(bf16)@+25165824 ; later osum@+0, last@+8388608
  size_t o_RB    = alloc(25165824ull);        // xp1(f16)@+0, hs1@+12582912 ; later qkv2@+0
  size_t o_tfea  = alloc(16384ull*256*2);     // text_fea bf16
  size_t o_qkv1  = alloc(16384ull*768*2);     // later logits (f32 [16384][192]) @ +0
  size_t o_cfea  = alloc(16384ull*256*2);
  size_t o_qkv0  = alloc(128ull*768*2);
  size_t o_loss  = alloc(16384ull*4);
  (void)ws_size; (void)in_sizes; (void)n_in; (void)out_size;

  unsigned short* g1Wih_bf = (unsigned short*)(ws + o_g1Wih);
  unsigned short* tlW_bf   = (unsigned short*)(ws + o_tlW);
  unsigned short* g2Wih_bf = (unsigned short*)(ws + o_g2Wih);
  f16*            g2Whh_f  = (f16*)(ws + o_g2Whh);
  unsigned short* clW_bf   = (unsigned short*)(ws + o_clW);
  unsigned short* aWin_bf  = (unsigned short*)(ws + o_aWin);
  unsigned short* aWout_bf = (unsigned short*)(ws + o_aWout);
  unsigned short* imgW_bf  = (unsigned short*)(ws + o_imgW);
  unsigned short* predW_bf = (unsigned short*)(ws + o_predW);
  float*          predb_p  = (float*)(ws + o_predb);
  unsigned short* img_fea  = (unsigned short*)(ws + o_imgfea);
  float*          meanb    = (float*)(ws + o_mean);
  float*          len_info = (float*)(ws + o_len);
  f16*            xp2      = (f16*)(ws + o_R0);
  unsigned short* hs2      = (unsigned short*)(ws + o_R0 + 25165824ull);
  unsigned short* osum     = (unsigned short*)(ws + o_R0);
  unsigned short* lastb    = (unsigned short*)(ws + o_R0 + 8388608ull);
  f16*            xp1      = (f16*)(ws + o_RB);
  unsigned short* hs1      = (unsigned short*)(ws + o_RB + 12582912ull);
  unsigned short* qkv2     = (unsigned short*)(ws + o_RB);
  unsigned short* tfea     = (unsigned short*)(ws + o_tfea);
  unsigned short* qkv1     = (unsigned short*)(ws + o_qkv1);
  float*          logits   = (float*)(ws + o_qkv1);
  unsigned short* cfea     = (unsigned short*)(ws + o_cfea);
  unsigned short* qkv0     = (unsigned short*)(ws + o_qkv0);
  float*          loss_raw = (float*)(ws + o_loss);
  float*          outp     = (float*)d_out;

  // one fused weight-conversion launch (8 segments)
  conv_all_k<<<2016, 256, 0, stream>>>(
      g1_Wih, tl_W, g2_Wih, g2_Whh, cl_W, a_Win, a_Wout, img_W,
      g1Wih_bf, tlW_bf, g2Wih_bf, g2Whh_f, clW_bf, aWin_bf, aWout_bf, imgW_bf);
  pred_pad_k<<<192, 256, 0, stream>>>(pred_W, pred_b, predW_bf, predb_p);

  // img encoder: Linear + BN + ReLU  -> img_fea (bf16)
  gemm128_k<2, true, 1><<<dim3(2, 1), 256, 0, stream>>>(
      img_emb, imgW_bf, img_b, img_g, img_be, img_m, img_v, img_fea, 128, 256, 2048);

  // xp1 = text_embs @ g1_Wih^T + bih  -> f16
  gemm128_k<1, false, 1><<<dim3(3, 128), 256, 0, stream>>>(
      text_embs, g1Wih_bf, g1_bih, nullptr, nullptr, nullptr, nullptr, xp1, 16384, 384, 2048);

  // GRU1 scan -> relu(h) bf16  (512 threads, round-15 config)
  gru1_scan_k<<<128, 512, 0, stream>>>(g1_Whh, g1_bhh, xp1, hs1);

  // tl: Linear + BN + ReLU -> text_fea
  gemm128_k<2, true, 0><<<dim3(2, 128), 256, 0, stream>>>(
      hs1, tlW_bf, tl_b, t_g, t_be, t_m, t_v, tfea, 16384, 256, 128);

  // mean over timesteps (contrast folded into xp2 staging)
  mean_k<<<128, 256, 0, stream>>>(tfea, len_mask, meanb, len_info);

  // xp2 = (tfea - mean) @ g2_Wih^T + bih   (A_MODE=2: subtract mean during staging)
  gemm128_k<1, false, 2><<<dim3(6, 128), 256, 0, stream>>>(
      tfea, g2Wih_bf, g2_bih, nullptr, nullptr, meanb, nullptr, xp2, 16384, 768, 256);

  // GRU2 scan (r,z in regs; n streamed from L2; h only in LDS)
  gru2_scan_k<<<128, 512, 0, stream>>>(g2Whh_f, g2_bhh, xp2, hs2);

  // cl: Linear + BN + ReLU -> contrast_fea
  gemm128_k<2, true, 0><<<dim3(2, 128), 256, 0, stream>>>(
      hs2, clW_bf, cl_b, c_g, c_be, c_m, c_v, cfea, 16384, 256, 256);

  // fused qkv projections: tfea->qkv1, cfea->qkv2, img_fea->qkv0 (one launch)
  gemmqkv_k<<<dim3(6, 257), 256, 0, stream>>>(
      tfea, cfea, img_fea, aWin_bf, a_bin, qkv1, qkv2, qkv0);

  // fused 3x3 attention -> mean over tokens (pre-projection)
  attn_k<<<128, 256, 0, stream>>>(qkv0, qkv1, qkv2, osum);

  // output projection (applied to token-mean; linearity) -> last
  gemm128_k<2, false, 0><<<dim3(2, 128), 256, 0, stream>>>(
      osum, aWout_bf, a_bout, nullptr, nullptr, nullptr, nullptr, lastb, 16384, 256, 256);

  // logits (N padded to 192) — 64-tile kernel
  gemm_k<0, false, false><<<dim3(3, 256), 256, 0, stream>>>(
      lastb, predW_bf, predb_p, nullptr, nullptr, nullptr, nullptr, logits, 16384, 192, 256);

  // per-row CE loss, then masked mean
  loss_k<<<16384, 64, 0, stream>>>(logits, label_mask, labels, loss_raw);
  final_k<<<1, 256, 0, stream>>>(loss_raw, len_mask, len_info, outp);
}

// Round 19
// 556.904 us; speedup vs baseline: 1.1591x; 1.0705x over previous
//
#include <hip/hip_runtime.h>

// ---------------- types & helpers ----------------
typedef __attribute__((ext_vector_type(8))) short short8;   // 8 bf16 (4 VGPR)
typedef __attribute__((ext_vector_type(4))) float f32x4;
typedef _Float16 f16;
typedef __attribute__((ext_vector_type(2))) _Float16 f16x2;
typedef __attribute__((ext_vector_type(8))) _Float16 f16x8;

__device__ inline float bf2f(unsigned short u){
  union{float f; unsigned u32;} x; x.u32 = ((unsigned)u) << 16; return x.f;
}
__device__ inline unsigned short f2bf(float f){
  union{float f; unsigned u;} x; x.f = f;
  unsigned r = (x.u + 0x7FFFu + ((x.u >> 16) & 1u)) >> 16;
  return (unsigned short)r;
}

#if defined(__has_builtin)
#  if __has_builtin(__builtin_amdgcn_fdot2)
#    define HAS_FDOT2 1
#  endif
#endif
__device__ inline float dot2f(f16x2 a, f16x2 b, float c){
#ifdef HAS_FDOT2
  return __builtin_amdgcn_fdot2(a, b, c, false);
#else
  return c + (float)a.x * (float)b.x + (float)a.y * (float)b.y;
#endif
}
__device__ inline f16x2 asf16x2(int v){ return __builtin_bit_cast(f16x2, v); }
__device__ inline int pack2(float lo, float hi){
  f16x2 p = f16x2{(f16)lo, (f16)hi};
  return __builtin_bit_cast(int, p);
}

__device__ inline float sigmoidf_(float x){ return 1.f / (1.f + __expf(-x)); }
__device__ inline float tanh_fast(float x){ float e = __expf(2.f * x); return 1.f - 2.f / (e + 1.f); }

// DPP quad-permute butterfly adds (VALU pipe)
__device__ inline float dpp_xor1(float x){
  return __int_as_float(__builtin_amdgcn_update_dpp(0, __float_as_int(x), 0xB1, 0xF, 0xF, true));
}
__device__ inline float dpp_xor2(float x){
  return __int_as_float(__builtin_amdgcn_update_dpp(0, __float_as_int(x), 0x4E, 0xF, 0xF, true));
}

__device__ inline void load8bf(const unsigned short* p, float* o){
  uint4 q = *(const uint4*)p;
  o[0]=bf2f((unsigned short)(q.x & 0xffffu)); o[1]=bf2f((unsigned short)(q.x >> 16));
  o[2]=bf2f((unsigned short)(q.y & 0xffffu)); o[3]=bf2f((unsigned short)(q.y >> 16));
  o[4]=bf2f((unsigned short)(q.z & 0xffffu)); o[5]=bf2f((unsigned short)(q.z >> 16));
  o[6]=bf2f((unsigned short)(q.w & 0xffffu)); o[7]=bf2f((unsigned short)(q.w >> 16));
}

// async global->LDS, 16 bytes per lane (lds dest = wave-uniform base + lane*16)
#define GLL16(g, l) __builtin_amdgcn_global_load_lds(                      \
    (const __attribute__((address_space(1))) void*)(g),                    \
    (__attribute__((address_space(3))) void*)(l), 16, 0, 0)

// ---------------- fused weight conversion (8 segments, one launch) ----------------
__global__ __launch_bounds__(256) void conv_all_k(
    const float* __restrict__ s0, const float* __restrict__ s1,
    const float* __restrict__ s2, const float* __restrict__ s3,
    const float* __restrict__ s4, const float* __restrict__ s5,
    const float* __restrict__ s6, const float* __restrict__ s7,
    unsigned short* __restrict__ d0, unsigned short* __restrict__ d1,
    unsigned short* __restrict__ d2, f16* __restrict__ d3,
    unsigned short* __restrict__ d4, unsigned short* __restrict__ d5,
    unsigned short* __restrict__ d6, unsigned short* __restrict__ d7)
{
  int i = blockIdx.x * 256 + threadIdx.x;
  if (i >= 516096) return;
  const float* src; int local; int mode = 0; unsigned short* dst = nullptr; f16* dstf = nullptr;
  if (i < 196608)      { src = s0; local = i;           dst = d0; }
  else if (i < 204800) { src = s1; local = i - 196608;  dst = d1; }
  else if (i < 253952) { src = s2; local = i - 204800;  dst = d2; }
  else if (i < 303104) { src = s3; local = i - 253952;  dstf = d3; mode = 1; }
  else if (i < 319488) { src = s4; local = i - 303104;  dst = d4; }
  else if (i < 368640) { src = s5; local = i - 319488;  dst = d5; }
  else if (i < 385024) { src = s6; local = i - 368640;  dst = d6; }
  else                 { src = s7; local = i - 385024;  dst = d7; }
  float4 v = ((const float4*)src)[local];
  if (mode == 0) {
    union { unsigned short s[4]; uint2 q; } u;
    u.s[0]=f2bf(v.x); u.s[1]=f2bf(v.y); u.s[2]=f2bf(v.z); u.s[3]=f2bf(v.w);
    ((uint2*)dst)[local] = u.q;
  } else {
    union { f16 s[4]; uint2 q; } u;
    u.s[0]=(f16)v.x; u.s[1]=(f16)v.y; u.s[2]=(f16)v.z; u.s[3]=(f16)v.w;
    ((uint2*)dstf)[local] = u.q;
  }
}

// pred_W [190][256] -> [192][256] zero-padded bf16; pred_b -> [192] zero-padded f32
__global__ __launch_bounds__(256) void pred_pad_k(const float* __restrict__ W,
                                                  const float* __restrict__ b,
                                                  unsigned short* __restrict__ Wd,
                                                  float* __restrict__ bd){
  int i = blockIdx.x * 256 + threadIdx.x;   // 192*256 threads
  int j = i >> 8;
  Wd[i] = (j < 190) ? f2bf(W[i]) : (unsigned short)0;
  if (i < 192) bd[i] = (i < 190) ? b[i] : 0.f;
}

// ---------------- 128x128-tile MFMA GEMM (m97 structure) ----------------
// A_MODE: 0 = bf16 via global_load_lds; 1 = f32 reg-convert; 2 = bf16 minus mean.
// MEAN_OUT: fold column-mean (over the 128 rows = timesteps of batch bm>>7) into epilogue.
template<int OUT_T, bool BN, int A_MODE, bool MEAN_OUT>
__global__ __launch_bounds__(256) void gemm128_k(
    const void* __restrict__ Ap, const unsigned short* __restrict__ Bw,
    const float* __restrict__ bias,
    const float* __restrict__ gam, const float* __restrict__ bet,
    const float* __restrict__ mu,  const float* __restrict__ var,
    void* __restrict__ Cp, int M, int N, int K,
    const float* __restrict__ lmask, float* __restrict__ mean_out,
    float* __restrict__ len_out)
{
  __shared__ __align__(16) unsigned short As[4096];   // [128][32]
  __shared__ __align__(16) unsigned short Bs[4096];
  __shared__ float msh[2][128];
  __shared__ float lsum[128];
  __shared__ float lenshv;
  const int tid  = threadIdx.x;
  const int lane = tid & 63, wid = tid >> 6;
  const int wm = wid & 1, wn = wid >> 1;
  const int bm = blockIdx.y << 7, bn = blockIdx.x << 7;
  const int rA = tid >> 2, seg = tid & 3;

  if (MEAN_OUT) {
    if (tid < 128) lsum[tid] = lmask[(size_t)(bm >> 7) * 128 + tid];
    __syncthreads();
    if (tid < 64) lsum[tid] += lsum[tid + 64];
    __syncthreads();
    if (tid == 0) { float s = 0.f; for (int i = 0; i < 64; i++) s += lsum[i]; lenshv = s; }
    __syncthreads();
  }

  f32x4 acc[4][4];
  #pragma unroll
  for (int i = 0; i < 4; i++)
    #pragma unroll
    for (int j = 0; j < 4; j++)
      acc[i][j] = f32x4{0.f, 0.f, 0.f, 0.f};

  const unsigned short* Abf = (const unsigned short*)Ap;
  const float* Af = (const float*)Ap;
  char* asb = (char*)As;
  char* bsb = (char*)Bs;
  char* asw = asb + wid * 1024;
  char* bsw = bsb + wid * 1024;

  for (int k0 = 0; k0 < K; k0 += 32) {
    if (A_MODE == 1) {
      #pragma unroll
      for (int beta = 0; beta < 2; beta++) {
        const float* src = Af + (size_t)(bm + rA + beta * 64) * K + k0 + seg * 8;
        float4 v0 = *(const float4*)src;
        float4 v1 = *(const float4*)(src + 4);
        union { unsigned short s[8]; uint4 q; } u;
        u.s[0]=f2bf(v0.x); u.s[1]=f2bf(v0.y); u.s[2]=f2bf(v0.z); u.s[3]=f2bf(v0.w);
        u.s[4]=f2bf(v1.x); u.s[5]=f2bf(v1.y); u.s[6]=f2bf(v1.z); u.s[7]=f2bf(v1.w);
        *(uint4*)(asb + beta * 4096 + tid * 16) = u.q;
      }
    } else if (A_MODE == 2) {
      const float* mrow = mu + (size_t)(bm >> 7) * 256 + k0 + seg * 8;
      float4 m0 = *(const float4*)mrow;
      float4 m1 = *(const float4*)(mrow + 4);
      #pragma unroll
      for (int beta = 0; beta < 2; beta++) {
        const unsigned short* src = Abf + (size_t)(bm + rA + beta * 64) * K + k0 + seg * 8;
        float av[8];
        load8bf(src, av);
        union { unsigned short s[8]; uint4 q; } u;
        u.s[0]=f2bf(av[0]-m0.x); u.s[1]=f2bf(av[1]-m0.y); u.s[2]=f2bf(av[2]-m0.z); u.s[3]=f2bf(av[3]-m0.w);
        u.s[4]=f2bf(av[4]-m1.x); u.s[5]=f2bf(av[5]-m1.y); u.s[6]=f2bf(av[6]-m1.z); u.s[7]=f2bf(av[7]-m1.w);
        *(uint4*)(asb + beta * 4096 + tid * 16) = u.q;
      }
    } else {
      GLL16(Abf + (size_t)(bm + rA)      * K + k0 + seg * 8, asw);
      GLL16(Abf + (size_t)(bm + rA + 64) * K + k0 + seg * 8, asw + 4096);
    }
    GLL16(Bw + (size_t)(bn + rA)      * K + k0 + seg * 8, bsw);
    GLL16(Bw + (size_t)(bn + rA + 64) * K + k0 + seg * 8, bsw + 4096);
    __syncthreads();

    short8 a[4], b[4];
    #pragma unroll
    for (int f = 0; f < 4; f++) {
      int ra = wm * 64 + f * 16 + (lane & 15);
      a[f] = *(const short8*)(asb + ra * 64 + (lane >> 4) * 16);
      int rb = wn * 64 + f * 16 + (lane & 15);
      b[f] = *(const short8*)(bsb + rb * 64 + (lane >> 4) * 16);
    }
    #pragma unroll
    for (int fm = 0; fm < 4; fm++)
      #pragma unroll
      for (int fn = 0; fn < 4; fn++)
        acc[fm][fn] = __builtin_amdgcn_mfma_f32_16x16x32_bf16(a[fm], b[fn], acc[fm][fn], 0, 0, 0);
    __syncthreads();
  }

  #pragma unroll
  for (int fn = 0; fn < 4; fn++) {
    int col = bn + wn * 64 + fn * 16 + (lane & 15);
    float bs = bias[col];
    float sc = 1.f, sh = 0.f;
    if (BN) { float s = gam[col] * rsqrtf(var[col] + 1e-5f); sc = s; sh = bet[col] - mu[col] * s; }
    float colacc = 0.f;
    #pragma unroll
    for (int fm = 0; fm < 4; fm++) {
      int row = bm + wm * 64 + fm * 16 + ((lane >> 4) << 2);
      #pragma unroll
      for (int j = 0; j < 4; j++) {
        float v = acc[fm][fn][j] + bs;
        if (BN) { v = v * sc + sh; v = fmaxf(v, 0.f); }
        size_t idx = (size_t)(row + j) * N + col;
        if (OUT_T == 1) ((f16*)Cp)[idx] = (f16)v;
        else            ((unsigned short*)Cp)[idx] = f2bf(v);
        if (MEAN_OUT) colacc += v;
      }
    }
    if (MEAN_OUT) {
      colacc += __shfl_xor(colacc, 16);
      colacc += __shfl_xor(colacc, 32);
      if ((lane >> 4) == 0) msh[wm][wn * 64 + fn * 16 + lane] = colacc;
    }
  }
  if (MEAN_OUT) {
    __syncthreads();
    if (tid < 128) {
      float tot = msh[0][tid] + msh[1][tid];
      mean_out[(size_t)(bm >> 7) * 256 + bn + tid] = tot / lenshv;
    }
    if (bn == 0 && tid == 0) len_out[bm >> 7] = lenshv;
  }
}

// ---------------- fused QKV GEMM: 3 sources x same B (aWin), N=768, K=256 ----------------
__global__ __launch_bounds__(256) void gemmqkv_k(
    const unsigned short* __restrict__ tfea, const unsigned short* __restrict__ cfea,
    const unsigned short* __restrict__ imgf, const unsigned short* __restrict__ Bw,
    const float* __restrict__ bias,
    unsigned short* __restrict__ q1, unsigned short* __restrict__ q2,
    unsigned short* __restrict__ q0)
{
  const int N = 768, K = 256;
  __shared__ __align__(16) unsigned short As[4096];
  __shared__ __align__(16) unsigned short Bs[4096];
  const int tid  = threadIdx.x;
  const int lane = tid & 63, wid = tid >> 6;
  const int wm = wid & 1, wn = wid >> 1;
  const int y = blockIdx.y;
  const unsigned short* Abf; unsigned short* Cp; int bm;
  if (y < 128)      { Abf = tfea; Cp = q1; bm = y << 7; }
  else if (y < 256) { Abf = cfea; Cp = q2; bm = (y - 128) << 7; }
  else              { Abf = imgf; Cp = q0; bm = 0; }
  const int bn = blockIdx.x << 7;
  const int rA = tid >> 2, seg = tid & 3;

  f32x4 acc[4][4];
  #pragma unroll
  for (int i = 0; i < 4; i++)
    #pragma unroll
    for (int j = 0; j < 4; j++)
      acc[i][j] = f32x4{0.f, 0.f, 0.f, 0.f};

  char* asb = (char*)As;
  char* bsb = (char*)Bs;
  char* asw = asb + wid * 1024;
  char* bsw = bsb + wid * 1024;

  for (int k0 = 0; k0 < K; k0 += 32) {
    GLL16(Abf + (size_t)(bm + rA)      * K + k0 + seg * 8, asw);
    GLL16(Abf + (size_t)(bm + rA + 64) * K + k0 + seg * 8, asw + 4096);
    GLL16(Bw + (size_t)(bn + rA)      * K + k0 + seg * 8, bsw);
    GLL16(Bw + (size_t)(bn + rA + 64) * K + k0 + seg * 8, bsw + 4096);
    __syncthreads();

    short8 a[4], b[4];
    #pragma unroll
    for (int f = 0; f < 4; f++) {
      int ra = wm * 64 + f * 16 + (lane & 15);
      a[f] = *(const short8*)(asb + ra * 64 + (lane >> 4) * 16);
      int rb = wn * 64 + f * 16 + (lane & 15);
      b[f] = *(const short8*)(bsb + rb * 64 + (lane >> 4) * 16);
    }
    #pragma unroll
    for (int fm = 0; fm < 4; fm++)
      #pragma unroll
      for (int fn = 0; fn < 4; fn++)
        acc[fm][fn] = __builtin_amdgcn_mfma_f32_16x16x32_bf16(a[fm], b[fn], acc[fm][fn], 0, 0, 0);
    __syncthreads();
  }

  #pragma unroll
  for (int fn = 0; fn < 4; fn++) {
    int col = bn + wn * 64 + fn * 16 + (lane & 15);
    float bs = bias[col];
    #pragma unroll
    for (int fm = 0; fm < 4; fm++) {
      int row = bm + wm * 64 + fm * 16 + ((lane >> 4) << 2);
      #pragma unroll
      for (int j = 0; j < 4; j++) {
        float v = acc[fm][fn][j] + bs;
        Cp[(size_t)(row + j) * N + col] = f2bf(v);
      }
    }
  }
}

// ---------------- 64-tile MFMA GEMM (kept for logits, N=192) ----------------
template<int OUT_T, bool BN, bool AF32>
__global__ __launch_bounds__(256) void gemm_k(
    const void* __restrict__ Ap, const unsigned short* __restrict__ Bw,
    const float* __restrict__ bias,
    const float* __restrict__ gam, const float* __restrict__ bet,
    const float* __restrict__ mu,  const float* __restrict__ var,
    void* __restrict__ Cp, int M, int N, int K)
{
  __shared__ unsigned short As[64][40];
  __shared__ unsigned short Bs[64][40];
  const int tid  = threadIdx.x;
  const int lane = tid & 63, wid = tid >> 6;
  const int wm = wid & 1, wn = wid >> 1;
  const int bm = blockIdx.y << 6, bn = blockIdx.x << 6;
  const int srow = tid >> 2, sseg = tid & 3;

  f32x4 acc[2][2];
  #pragma unroll
  for (int i = 0; i < 2; i++)
    #pragma unroll
    for (int j = 0; j < 2; j++)
      acc[i][j] = f32x4{0.f, 0.f, 0.f, 0.f};

  const unsigned short* Abf = (const unsigned short*)Ap;
  const float* Af = (const float*)Ap;

  for (int k0 = 0; k0 < K; k0 += 32) {
    if (AF32) {
      const float* src = Af + (size_t)(bm + srow) * K + k0 + sseg * 8;
      float4 v0 = *(const float4*)(src);
      float4 v1 = *(const float4*)(src + 4);
      union { unsigned short s[8]; uint4 q; } u;
      u.s[0]=f2bf(v0.x); u.s[1]=f2bf(v0.y); u.s[2]=f2bf(v0.z); u.s[3]=f2bf(v0.w);
      u.s[4]=f2bf(v1.x); u.s[5]=f2bf(v1.y); u.s[6]=f2bf(v1.z); u.s[7]=f2bf(v1.w);
      *(uint4*)&As[srow][sseg * 8] = u.q;
    } else {
      *(uint4*)&As[srow][sseg * 8] =
          *(const uint4*)(Abf + (size_t)(bm + srow) * K + k0 + sseg * 8);
    }
    *(uint4*)&Bs[srow][sseg * 8] =
        *(const uint4*)(Bw + (size_t)(bn + srow) * K + k0 + sseg * 8);
    __syncthreads();

    short8 a0 = *(const short8*)&As[wm * 32 +      (lane & 15)][(lane >> 4) * 8];
    short8 a1 = *(const short8*)&As[wm * 32 + 16 + (lane & 15)][(lane >> 4) * 8];
    short8 b0 = *(const short8*)&Bs[wn * 32 +      (lane & 15)][(lane >> 4) * 8];
    short8 b1 = *(const short8*)&Bs[wn * 32 + 16 + (lane & 15)][(lane >> 4) * 8];
    acc[0][0] = __builtin_amdgcn_mfma_f32_16x16x32_bf16(a0, b0, acc[0][0], 0, 0, 0);
    acc[0][1] = __builtin_amdgcn_mfma_f32_16x16x32_bf16(a0, b1, acc[0][1], 0, 0, 0);
    acc[1][0] = __builtin_amdgcn_mfma_f32_16x16x32_bf16(a1, b0, acc[1][0], 0, 0, 0);
    acc[1][1] = __builtin_amdgcn_mfma_f32_16x16x32_bf16(a1, b1, acc[1][1], 0, 0, 0);
    __syncthreads();
  }

  #pragma unroll
  for (int fn = 0; fn < 2; fn++) {
    int col = bn + wn * 32 + fn * 16 + (lane & 15);
    float bs = bias[col];
    float sc = 1.f, sh = 0.f;
    if (BN) { float s = gam[col] * rsqrtf(var[col] + 1e-5f); sc = s; sh = bet[col] - mu[col] * s; }
    #pragma unroll
    for (int fm = 0; fm < 2; fm++) {
      int row = bm + wm * 32 + fm * 16 + ((lane >> 4) << 2);
      #pragma unroll
      for (int j = 0; j < 4; j++) {
        float v = acc[fm][fn][j] + bs;
        if (BN) { v = v * sc + sh; v = fmaxf(v, 0.f); }
        size_t idx = (size_t)(row + j) * N + col;
        if (OUT_T == 0)      ((float*)Cp)[idx] = v;
        else if (OUT_T == 1) ((f16*)Cp)[idx]   = (f16)v;
        else                 ((unsigned short*)Cp)[idx] = f2bf(v);
      }
    }
  }
}

// ---------------- GRU scans ----------------
// GRU2 (r,z in opaque regs; n streamed from L2; h-only LDS): 512 thr, jj=tid>>1, kh=tid&1.
__global__ __launch_bounds__(512, 2) void gru2_scan_k(
    const f16* __restrict__ Wf,              // [768][256] f16
    const float* __restrict__ bhh,
    const f16* __restrict__ xp, unsigned short* __restrict__ hs_relu)
{
  const int b = blockIdx.x;
  const int tid = threadIdx.x;
  const int jj = tid >> 1, kh = tid & 1;
  __shared__ __align__(16) f16 hbuf[2][256];

  int wri[64], wzi[64];
  #pragma unroll
  for (int i = 0; i < 16; i++) {
    const int kb = kh * 128 + i * 8;
    uint4 q;
    q = *(const uint4*)&Wf[(size_t)(jj      ) * 256 + kb];
    wri[4*i+0] = (int)q.x; wri[4*i+1] = (int)q.y; wri[4*i+2] = (int)q.z; wri[4*i+3] = (int)q.w;
    q = *(const uint4*)&Wf[(size_t)(jj + 256) * 256 + kb];
    wzi[4*i+0] = (int)q.x; wzi[4*i+1] = (int)q.y; wzi[4*i+2] = (int)q.z; wzi[4*i+3] = (int)q.w;
  }
  #pragma unroll
  for (int i = 0; i < 64; i++)
    asm volatile("" : "+v"(wri[i]), "+v"(wzi[i]));

  const f16* nsrc = Wf + (size_t)(512 + jj) * 256 + kh * 128;

  const float br = bhh[jj], bz = bhh[jj + 256], bn2 = bhh[jj + 512];
  if (tid < 256) hbuf[0][tid] = (f16)0.f;
  float hprev = 0.f;
  f16 pxr = (f16)0.f, pxz = (f16)0.f, pxn = (f16)0.f;
  if (kh == 0) {
    const f16* x0 = xp + (size_t)(b * 128) * 768;
    pxr = x0[jj]; pxz = x0[256 + jj]; pxn = x0[512 + jj];
  }
  __syncthreads();
  int cur = 0;
  for (int t = 0; t < 128; t++) {
    float xr = (float)pxr, xz = (float)pxz, xn = (float)pxn;
    if (kh == 0) {
      const int tn = (t < 127) ? (t + 1) : 127;
      const f16* xnr = xp + (size_t)(b * 128 + tn) * 768;
      pxr = xnr[jj]; pxz = xnr[256 + jj]; pxn = xnr[512 + jj];
    }
    uint4 nb[4];
    #pragma unroll
    for (int c = 0; c < 4; c++) nb[c] = *(const uint4*)(nsrc + c * 8);

    const char* hb = (const char*)hbuf[cur] + kh * 256;
    float ar = 0.f, az = 0.f, an = 0.f;
    #pragma unroll
    for (int i = 0; i < 16; i++) {
      f16x8 hv = *(const f16x8*)(hb + i * 16);
      f16x8 nv = __builtin_bit_cast(f16x8, nb[i & 3]);
      if (i < 12) nb[i & 3] = *(const uint4*)(nsrc + (i + 4) * 8);
      #pragma unroll
      for (int u = 0; u < 4; u++) {
        f16x2 hp = f16x2{hv[2*u], hv[2*u+1]};
        ar = dot2f(asf16x2(wri[4*i+u]), hp, ar);
        az = dot2f(asf16x2(wzi[4*i+u]), hp, az);
        an = dot2f(f16x2{nv[2*u], nv[2*u+1]}, hp, an);
      }
    }
    ar += dpp_xor1(ar);
    az += dpp_xor1(az);
    an += dpp_xor1(an);
    if (kh == 0) {
      float r = sigmoidf_(xr + ar + br);
      float z = sigmoidf_(xz + az + bz);
      float n = tanh_fast(xn + r * (an + bn2));
      float hnew = (1.f - z) * n + z * hprev;
      hprev = hnew;
      hbuf[cur ^ 1][jj] = (f16)hnew;
      hs_relu[(size_t)(b * 128 + t) * 256 + jj] = f2bf(fmaxf(hnew, 0.f));
    }
    __syncthreads();
    cur ^= 1;
  }
}

// GRU1 (round-15 best): H=128, gates 384. 512 thr: jj = tid>>2, kh = tid&3.
__global__ __launch_bounds__(512, 4) void gru1_scan_k(
    const float* __restrict__ Whh, const float* __restrict__ bhh,
    const f16* __restrict__ xp, unsigned short* __restrict__ hs_relu)
{
  const int b = blockIdx.x;
  const int tid = threadIdx.x;
  const int jj = tid >> 2, kh = tid & 3;
  __shared__ __align__(16) f16 hbuf[2][128];

  int wri[16], wzi[16], wni[16];
  #pragma unroll
  for (int i = 0; i < 4; i++) {
    const int kb = kh * 32 + i * 8;
    float4 f0, f1;
    f0 = *(const float4*)&Whh[(size_t)(jj      ) * 128 + kb];
    f1 = *(const float4*)&Whh[(size_t)(jj      ) * 128 + kb + 4];
    wri[4*i+0] = pack2(f0.x, f0.y); wri[4*i+1] = pack2(f0.z, f0.w);
    wri[4*i+2] = pack2(f1.x, f1.y); wri[4*i+3] = pack2(f1.z, f1.w);
    f0 = *(const float4*)&Whh[(size_t)(jj + 128) * 128 + kb];
    f1 = *(const float4*)&Whh[(size_t)(jj + 128) * 128 + kb + 4];
    wzi[4*i+0] = pack2(f0.x, f0.y); wzi[4*i+1] = pack2(f0.z, f0.w);
    wzi[4*i+2] = pack2(f1.x, f1.y); wzi[4*i+3] = pack2(f1.z, f1.w);
    f0 = *(const float4*)&Whh[(size_t)(jj + 256) * 128 + kb];
    f1 = *(const float4*)&Whh[(size_t)(jj + 256) * 128 + kb + 4];
    wni[4*i+0] = pack2(f0.x, f0.y); wni[4*i+1] = pack2(f0.z, f0.w);
    wni[4*i+2] = pack2(f1.x, f1.y); wni[4*i+3] = pack2(f1.z, f1.w);
  }
  #pragma unroll
  for (int i = 0; i < 16; i++)
    asm volatile("" : "+v"(wri[i]), "+v"(wzi[i]), "+v"(wni[i]));

  const float br = bhh[jj], bz = bhh[jj + 128], bn2 = bhh[jj + 256];
  if (tid < 128) hbuf[0][tid] = (f16)0.f;
  float hprev = 0.f;
  f16 pxr = (f16)0.f, pxz = (f16)0.f, pxn = (f16)0.f;
  if (kh == 0) {
    const f16* x0 = xp + (size_t)(b * 128) * 384;
    pxr = x0[jj]; pxz = x0[128 + jj]; pxn = x0[256 + jj];
  }
  __syncthreads();
  int cur = 0;
  for (int t = 0; t < 128; t++) {
    float xr = (float)pxr, xz = (float)pxz, xn = (float)pxn;
    if (kh == 0) {
      const int tn = (t < 127) ? (t + 1) : 127;
      const f16* xnr = xp + (size_t)(b * 128 + tn) * 384;
      pxr = xnr[jj]; pxz = xnr[128 + jj]; pxn = xnr[256 + jj];
    }
    const char* hb = (const char*)hbuf[cur] + kh * 64;
    float ar = 0.f, az = 0.f, an = 0.f;
    #pragma unroll
    for (int c = 0; c < 4; c++) {
      f16x8 hv = *(const f16x8*)(hb + c * 16);
      #pragma unroll
      for (int u = 0; u < 4; u++) {
        f16x2 hp = f16x2{hv[2*u], hv[2*u+1]};
        ar = dot2f(asf16x2(wri[4*c+u]), hp, ar);
        az = dot2f(asf16x2(wzi[4*c+u]), hp, az);
        an = dot2f(asf16x2(wni[4*c+u]), hp, an);
      }
    }
    ar += dpp_xor1(ar); ar += dpp_xor2(ar);
    az += dpp_xor1(az); az += dpp_xor2(az);
    an += dpp_xor1(an); an += dpp_xor2(an);
    if (kh == 0) {
      float r = sigmoidf_(xr + ar + br);
      float z = sigmoidf_(xz + az + bz);
      float n = tanh_fast(xn + r * (an + bn2));
      float hnew = (1.f - z) * n + z * hprev;
      hprev = hnew;
      hbuf[cur ^ 1][jj] = (f16)hnew;
      hs_relu[(size_t)(b * 128 + t) * 128 + jj] = f2bf(fmaxf(hnew, 0.f));
    }
    __syncthreads();
    cur ^= 1;
  }
}

// ---------------- fused 3-token attention (thread per (n, head)) ----------------
__global__ __launch_bounds__(256) void attn_k(const unsigned short* __restrict__ qkv0,
                                              const unsigned short* __restrict__ qkv1,
                                              const unsigned short* __restrict__ qkv2,
                                              unsigned short* __restrict__ osum){
  int i = blockIdx.x * 256 + threadIdx.x;   // 32768
  int h = i & 1; int n = i >> 1; int b = n >> 7;
  const unsigned short* t0 = qkv0 + (size_t)b * 768 + h * 128;
  const unsigned short* t1 = qkv1 + (size_t)n * 768 + h * 128;
  const unsigned short* t2 = qkv2 + (size_t)n * 768 + h * 128;
  float sc[3][3];
  #pragma unroll
  for (int a = 0; a < 3; a++)
    #pragma unroll
    for (int s = 0; s < 3; s++) sc[a][s] = 0.f;
  #pragma unroll 1
  for (int dc = 0; dc < 16; dc++) {
    float q[3][8], k[3][8];
    load8bf(t0 + dc * 8, q[0]); load8bf(t1 + dc * 8, q[1]); load8bf(t2 + dc * 8, q[2]);
    load8bf(t0 + 256 + dc * 8, k[0]); load8bf(t1 + 256 + dc * 8, k[1]); load8bf(t2 + 256 + dc * 8, k[2]);
    #pragma unroll
    for (int a = 0; a < 3; a++)
      #pragma unroll
      for (int s = 0; s < 3; s++) {
        float d = 0.f;
        #pragma unroll
        for (int e = 0; e < 8; e++) d += q[a][e] * k[s][e];
        sc[a][s] += d;
      }
  }
  const float scale = 0.08838834764831845f;   // 1/sqrt(128)
  float w[3] = {0.f, 0.f, 0.f};
  #pragma unroll
  for (int a = 0; a < 3; a++) {
    float s0 = sc[a][0] * scale, s1 = sc[a][1] * scale, s2 = sc[a][2] * scale;
    float m = fmaxf(s0, fmaxf(s1, s2));
    float e0 = __expf(s0 - m), e1 = __expf(s1 - m), e2 = __expf(s2 - m);
    float inv = 1.f / (e0 + e1 + e2);
    w[0] += e0 * inv; w[1] += e1 * inv; w[2] += e2 * inv;
  }
  w[0] *= (1.f / 3.f); w[1] *= (1.f / 3.f); w[2] *= (1.f / 3.f);
  unsigned short* op = osum + (size_t)n * 256 + h * 128;
  #pragma unroll 1
  for (int dc = 0; dc < 16; dc++) {
    float v0[8], v1[8], v2[8];
    load8bf(t0 + 512 + dc * 8, v0); load8bf(t1 + 512 + dc * 8, v1); load8bf(t2 + 512 + dc * 8, v2);
    union { unsigned short s[8]; uint4 q; } u;
    #pragma unroll
    for (int e = 0; e < 8; e++) u.s[e] = f2bf(w[0] * v0[e] + w[1] * v1[e] + w[2] * v2[e]);
    *(uint4*)(op + dc * 8) = u.q;
  }
}

// ---------------- softmax-CE loss per row ----------------
__global__ __launch_bounds__(64) void loss_k(const float* __restrict__ logits,
                                             const float* __restrict__ label_mask,
                                             const int* __restrict__ labels,
                                             float* __restrict__ loss_raw){
  int r = blockIdx.x; int j = threadIdx.x;
  int lab = labels[r];
  float l[3]; float m = -1e30f;
  #pragma unroll
  for (int q = 0; q < 3; q++) {
    int c = j + q * 64;
    float lv = (c < 190) ? logits[(size_t)r * 192 + c] : -1e30f;
    l[q] = lv; m = fmaxf(m, lv);
  }
  #pragma unroll
  for (int off = 32; off; off >>= 1) m = fmaxf(m, __shfl_xor(m, off));
  float se = 0.f, soh = 0.f, dot = 0.f;
  #pragma unroll
  for (int q = 0; q < 3; q++) {
    int c = j + q * 64;
    if (c < 190) {
      se += expf(l[q] - m);
      float oh = fmaxf(label_mask[(size_t)r * 190 + c], (c == lab) ? 1.f : 0.f);
      soh += oh; dot += oh * l[q];
    }
  }
  #pragma unroll
  for (int off = 32; off; off >>= 1) {
    se += __shfl_xor(se, off); soh += __shfl_xor(soh, off); dot += __shfl_xor(dot, off);
  }
  if (j == 0) loss_raw[r] = (m + logf(se)) * soh - dot;
}

__global__ __launch_bounds__(256) void final_k(const float* __restrict__ loss_raw,
                                               const float* __restrict__ len_mask,
                                               const float* __restrict__ len_info,
                                               float* __restrict__ out){
  __shared__ float sh[256];
  int t = threadIdx.x;
  float acc = 0.f;
  for (int i = t; i < 16384; i += 256) acc += loss_raw[i] * len_mask[i] / len_info[i >> 7];
  sh[t] = acc; __syncthreads();
  for (int s = 128; s; s >>= 1) { if (t < s) sh[t] += sh[t + s]; __syncthreads(); }
  if (t == 0) out[0] = sh[0] / 128.f;
}

// ---------------- launch ----------------
extern "C" void kernel_launch(void* const* d_in, const int* in_sizes, int n_in,
                              void* d_out, int out_size, void* d_ws, size_t ws_size,
                              hipStream_t stream)
{
  const float* img_emb    = (const float*)d_in[0];
  const float* text_embs  = (const float*)d_in[1];
  const float* len_mask   = (const float*)d_in[2];
  const float* label_mask = (const float*)d_in[3];
  const int*   labels     = (const int*)  d_in[4];
  const float* img_W   = (const float*)d_in[5];
  const float* img_b   = (const float*)d_in[6];
  const float* img_g   = (const float*)d_in[7];
  const float* img_be  = (const float*)d_in[8];
  const float* img_m   = (const float*)d_in[9];
  const float* img_v   = (const float*)d_in[10];
  const float* g1_Wih  = (const float*)d_in[11];
  const float* g1_Whh  = (const float*)d_in[12];
  const float* g1_bih  = (const float*)d_in[13];
  const float* g1_bhh  = (const float*)d_in[14];
  const float* tl_W    = (const float*)d_in[15];
  const float* tl_b    = (const float*)d_in[16];
  const float* t_g     = (const float*)d_in[17];
  const float* t_be    = (const float*)d_in[18];
  const float* t_m     = (const float*)d_in[19];
  const float* t_v     = (const float*)d_in[20];
  const float* g2_Wih  = (const float*)d_in[21];
  const float* g2_Whh  = (const float*)d_in[22];
  const float* g2_bih  = (const float*)d_in[23];
  const float* g2_bhh  = (const float*)d_in[24];
  const float* cl_W    = (const float*)d_in[25];
  const float* cl_b    = (const float*)d_in[26];
  const float* c_g     = (const float*)d_in[27];
  const float* c_be    = (const float*)d_in[28];
  const float* c_m     = (const float*)d_in[29];
  const float* c_v     = (const float*)d_in[30];
  const float* a_Win   = (const float*)d_in[31];
  const float* a_bin   = (const float*)d_in[32];
  const float* a_Wout  = (const float*)d_in[33];
  const float* a_bout  = (const float*)d_in[34];
  const float* pred_W  = (const float*)d_in[35];
  const float* pred_b  = (const float*)d_in[36];

  char* ws = (char*)d_ws;
  size_t o = 0;
  auto alloc = [&](size_t sz){ size_t r = o; o += (sz + 255) & ~(size_t)255; return r; };

  // bf16 weight copies
  size_t o_g1Wih = alloc(384ull*2048*2);
  size_t o_tlW   = alloc(256ull*128*2);
  size_t o_g2Wih = alloc(768ull*256*2);
  size_t o_g2Whh = alloc(768ull*256*2);      // f16 copy for gru2
  size_t o_clW   = alloc(256ull*256*2);
  size_t o_aWin  = alloc(768ull*256*2);
  size_t o_aWout = alloc(256ull*256*2);
  size_t o_imgW  = alloc(256ull*2048*2);
  size_t o_predW = alloc(192ull*256*2);
  size_t o_predb = alloc(192ull*4);
  size_t o_imgfea= alloc(128ull*256*2);      // bf16
  size_t o_mean  = alloc(128ull*256*4);
  size_t o_len   = alloc(128ull*4);
  size_t o_R0    = alloc(33554432ull);        // xp2(f16)@+0, hs2(bf16)@+25165824 ; later osum@+0, last@+8388608
  size_t o_RB    = alloc(25165824ull);        // xp1(f16)@+0, hs1@+12582912 ; later qkv2@+0
  size_t o_tfea  = alloc(16384ull*256*2);     // text_fea bf16
  size_t o_qkv1  = alloc(16384ull*768*2);     // later logits (f32 [16384][192]) @ +0
  size_t o_cfea  = alloc(16384ull*256*2);
  size_t o_qkv0  = alloc(128ull*768*2);
  size_t o_loss  = alloc(16384ull*4);
  (void)ws_size; (void)in_sizes; (void)n_in; (void)out_size;

  unsigned short* g1Wih_bf = (unsigned short*)(ws + o_g1Wih);
  unsigned short* tlW_bf   = (unsigned short*)(ws + o_tlW);
  unsigned short* g2Wih_bf = (unsigned short*)(ws + o_g2Wih);
  f16*            g2Whh_f  = (f16*)(ws + o_g2Whh);
  unsigned short* clW_bf   = (unsigned short*)(ws + o_clW);
  unsigned short* aWin_bf  = (unsigned short*)(ws + o_aWin);
  unsigned short* aWout_bf = (unsigned short*)(ws + o_aWout);
  unsigned short* imgW_bf  = (unsigned short*)(ws + o_imgW);
  unsigned short* predW_bf = (unsigned short*)(ws + o_predW);
  float*          predb_p  = (float*)(ws + o_predb);
  unsigned short* img_fea  = (unsigned short*)(ws + o_imgfea);
  float*          meanb    = (float*)(ws + o_mean);
  float*          len_info = (float*)(ws + o_len);
  f16*            xp2      = (f16*)(ws + o_R0);
  unsigned short* hs2      = (unsigned short*)(ws + o_R0 + 25165824ull);
  unsigned short* osum     = (unsigned short*)(ws + o_R0);
  unsigned short* lastb    = (unsigned short*)(ws + o_R0 + 8388608ull);
  f16*            xp1      = (f16*)(ws + o_RB);
  unsigned short* hs1      = (unsigned short*)(ws + o_RB + 12582912ull);
  unsigned short* qkv2     = (unsigned short*)(ws + o_RB);
  unsigned short* tfea     = (unsigned short*)(ws + o_tfea);
  unsigned short* qkv1     = (unsigned short*)(ws + o_qkv1);
  float*          logits   = (float*)(ws + o_qkv1);
  unsigned short* cfea     = (unsigned short*)(ws + o_cfea);
  unsigned short* qkv0     = (unsigned short*)(ws + o_qkv0);
  float*          loss_raw = (float*)(ws + o_loss);
  float*          outp     = (float*)d_out;

  // one fused weight-conversion launch (8 segments)
  conv_all_k<<<2016, 256, 0, stream>>>(
      g1_Wih, tl_W, g2_Wih, g2_Whh, cl_W, a_Win, a_Wout, img_W,
      g1Wih_bf, tlW_bf, g2Wih_bf, g2Whh_f, clW_bf, aWin_bf, aWout_bf, imgW_bf);
  pred_pad_k<<<192, 256, 0, stream>>>(pred_W, pred_b, predW_bf, predb_p);

  // img encoder: Linear + BN + ReLU  -> img_fea (bf16)
  gemm128_k<2, true, 1, false><<<dim3(2, 1), 256, 0, stream>>>(
      img_emb, imgW_bf, img_b, img_g, img_be, img_m, img_v, img_fea, 128, 256, 2048,
      nullptr, nullptr, nullptr);

  // xp1 = text_embs @ g1_Wih^T + bih  -> f16
  gemm128_k<1, false, 1, false><<<dim3(3, 128), 256, 0, stream>>>(
      text_embs, g1Wih_bf, g1_bih, nullptr, nullptr, nullptr, nullptr, xp1, 16384, 384, 2048,
      nullptr, nullptr, nullptr);

  // GRU1 scan -> relu(h) bf16  (512 threads, round-15 config)
  gru1_scan_k<<<128, 512, 0, stream>>>(g1_Whh, g1_bhh, xp1, hs1);

  // tl: Linear + BN + ReLU -> text_fea, with column-mean + len_info fused in epilogue
  gemm128_k<2, true, 0, true><<<dim3(2, 128), 256, 0, stream>>>(
      hs1, tlW_bf, tl_b, t_g, t_be, t_m, t_v, tfea, 16384, 256, 128,
      len_mask, meanb, len_info);

  // xp2 = (tfea - mean) @ g2_Wih^T + bih   (A_MODE=2: subtract mean during staging)
  gemm128_k<1, false, 2, false><<<dim3(6, 128), 256, 0, stream>>>(
      tfea, g2Wih_bf, g2_bih, nullptr, nullptr, meanb, nullptr, xp2, 16384, 768, 256,
      nullptr, nullptr, nullptr);

  // GRU2 scan (r,z in regs; n streamed from L2; h only in LDS)
  gru2_scan_k<<<128, 512, 0, stream>>>(g2Whh_f, g2_bhh, xp2, hs2);

  // cl: Linear + BN + ReLU -> contrast_fea
  gemm128_k<2, true, 0, false><<<dim3(2, 128), 256, 0, stream>>>(
      hs2, clW_bf, cl_b, c_g, c_be, c_m, c_v, cfea, 16384, 256, 256,
      nullptr, nullptr, nullptr);

  // fused qkv projections: tfea->qkv1, cfea->qkv2, img_fea->qkv0 (one launch)
  gemmqkv_k<<<dim3(6, 257), 256, 0, stream>>>(
      tfea, cfea, img_fea, aWin_bf, a_bin, qkv1, qkv2, qkv0);

  // fused 3x3 attention -> mean over tokens (pre-projection)
  attn_k<<<128, 256, 0, stream>>>(qkv0, qkv1, qkv2, osum);

  // output projection (applied to token-mean; linearity) -> last
  gemm128_k<2, false, 0, false><<<dim3(2, 128), 256, 0, stream>>>(
      osum, aWout_bf, a_bout, nullptr, nullptr, nullptr, nullptr, lastb, 16384, 256, 256,
      nullptr, nullptr, nullptr);

  // logits (N padded to 192) — 64-tile kernel
  gemm_k<0, false, false><<<dim3(3, 256), 256, 0, stream>>>(
      lastb, predW_bf, predb_p, nullptr, nullptr, nullptr, nullptr, logits, 16384, 192, 256);

  // per-row CE loss, then masked mean
  loss_k<<<16384, 64, 0, stream>>>(logits, label_mask, labels, loss_raw);
  final_k<<<1, 256, 0, stream>>>(loss_raw, len_mask, len_info, outp);
}